// Round 6
// baseline (934.657 us; speedup 1.0000x reference)
//
#include <hip/hip_runtime.h>
#include <hip/hip_bf16.h>
#include <hip/hip_fp16.h>

typedef unsigned short u16;
typedef __attribute__((ext_vector_type(8))) short short8;
typedef __attribute__((ext_vector_type(4))) float f32x4;

#define BN_EPS    1e-3f
#define RELAX     1.3f
#define SQRT_HALF 0.7071067811865476f

// packed-weight offsets (ushort units)
#define PK_G0_US     0
#define PK_G1_US     65536
#define PK_DEP_US    98304
#define PK_AT_US     360448
#define PK_WOUT_US   409600
#define PK_WOUTLO_US 413696
// ws byte offsets
#define OFF_SHIFT 835584
#define OFF_SCALE 848896
#define OFF_INSC  862208
#define OFF_INSH  863232

__device__ __forceinline__ u16 f2bf(float x){
  unsigned u = __float_as_uint(x);
  return (u16)((u + 0x7fffu + ((u >> 16) & 1u)) >> 16);
}
__device__ __forceinline__ float bf2f(u16 h){ return __uint_as_float(((unsigned)h) << 16); }
__device__ __forceinline__ float sigm(float x){ return 1.0f / (1.0f + __expf(-x)); }
__device__ __forceinline__ f32x4 splat4(float x){ f32x4 v; v[0]=x; v[1]=x; v[2]=x; v[3]=x; return v; }

// packed pair f32->bf16 (RTNE) -> one u32 (v_cvt_pk_bf16_f32)
__device__ __forceinline__ unsigned pk2(float a, float b){
  float2 t; t.x = a; t.y = b;
  union { __hip_bfloat162 h; unsigned u; } v;
  v.h = __float22bfloat162_rn(t);
  return v.u;
}

// ---------------- prep: BN scale/shift tables ----------------
__global__ void prep_bn(
  const float* in_g, const float* in_b, const float* in_m, const float* in_v,
  const float* sh_g, const float* sh_b, const float* sh_m, const float* sh_v,
  const float* dep_g, const float* dep_b, const float* dep_m, const float* dep_v,
  const float* at_g, const float* at_b, const float* at_m, const float* at_v,
  float* shiftT, float* scaleT, float* inSc, float* inSh)
{
  int r = blockIdx.x, f = threadIdx.x;
  if (r < 13) {
    const float *g, *bb, *mm, *vv;
    if (r < 2)       { g = sh_g + r*256;        bb = sh_b + r*256;        mm = sh_m + r*256;        vv = sh_v + r*256; }
    else if (r < 10) { int j = r-2;  g = dep_g + j*256; bb = dep_b + j*256; mm = dep_m + j*256; vv = dep_v + j*256; }
    else             { int j = r-10; g = at_g  + j*256; bb = at_b  + j*256; mm = at_m  + j*256; vv = at_v  + j*256; }
    float sc = g[f] * rsqrtf(vv[f] + BN_EPS);
    scaleT[r*256 + f] = sc;
    shiftT[r*256 + f] = bb[f] - mm[f]*sc;
  } else {
    float sc = in_g[f] * rsqrtf(in_v[f] + BN_EPS);
    inSc[f] = sc;
    inSh[f] = in_b[f] - in_m[f]*sc;
  }
}

// ---------------- prep: pack weights into MFMA A-fragment order (BN scale folded) ----------------
__global__ void prep_pack(
  const float* sh_W0, const float* sh_W1, const float* dep_W,
  const float* at_W, const float* Wout, const float* scaleT, u16* pk)
{
  int c = blockIdx.x*256 + threadIdx.x;   // 16B chunk id, 0..52223
  const float* W; int K, Nout, srow, base; bool lo = false;
  if (c < 8192)       { W = sh_W0; K = 256; Nout = 256; srow = 0;  base = 0; }
  else if (c < 12288) { W = sh_W1; K = 128; Nout = 256; srow = 1;  base = 8192; }
  else if (c < 45056) { int j = (c-12288) >> 12; W = dep_W + j*32768; K = 128; Nout = 256; srow = 2+j;  base = 12288 + j*4096; }
  else if (c < 51200) { int j = (c-45056) >> 11; W = at_W  + j*16384; K = 64;  Nout = 256; srow = 10+j; base = 45056 + j*2048; }
  else if (c < 51712) { W = Wout; K = 64; Nout = 64; srow = -1; base = 51200; }
  else                { W = Wout; K = 64; Nout = 64; srow = -1; base = 51712; lo = true; }
  int local = c - base;
  int lane  = local & 63;
  int t     = local >> 6;
  int KS    = K >> 5;
  int lsh   = (K == 256) ? 3 : (K == 128) ? 2 : 1;
  int ks    = t & (KS - 1);
  int mf    = t >> lsh;
  int feat  = mf*16 + (lane & 15);
  int k0    = ks*32 + ((lane >> 4) << 3);
  float scl = (srow < 0) ? 1.0f : scaleT[srow*256 + feat];
  u16 v[8];
  #pragma unroll
  for (int j = 0; j < 8; ++j) {
    float x = W[(size_t)(k0 + j)*Nout + feat] * scl;
    u16 h = f2bf(x);
    if (lo) h = f2bf(x - bf2f(h));
    v[j] = h;
  }
  ushort4* d4 = (ushort4*)(pk + (size_t)c*8);
  ushort4 p0; p0.x=v[0]; p0.y=v[1]; p0.z=v[2]; p0.w=v[3];
  ushort4 p1; p1.x=v[4]; p1.y=v[5]; p1.z=v[6]; p1.w=v[7];
  d4[0] = p0; d4[1] = p1;
}

// ---------------- main fused kernel helpers (4 waves, 4 m-frags/wave, 2 n-frags) ----------------
// wave w owns m-frags {w, w+4, w+8, w+12}; value cols = mi 0,1 (frags w,w+4),
// gate cols = mi 2,3 (frags w+8,w+12). n-frags cover 32 samples.
template<int KS, int LDB, int KOFF>
__device__ __forceinline__ void gemm4(const u16* __restrict__ pk, const u16* bufB,
                                      int w, int l15, int lg, int swzv, f32x4 acc[4][2])
{
  const int lane = lg*16 + l15;
  #pragma unroll 2
  for (int ks = 0; ks < KS; ++ks) {
    short8 b[2];
    #pragma unroll
    for (int nf = 0; nf < 2; ++nf) {
      int idx = (nf*16 + l15)*LDB + KOFF + ks*32 + lg*8;
      b[nf] = *(const short8*)(bufB + (idx ^ swzv));
    }
    short8 a[4];
    #pragma unroll
    for (int mi = 0; mi < 4; ++mi)
      a[mi] = *(const short8*)(pk + (size_t)(((w + 4*mi)*KS + ks)*64 + lane)*8);
    #pragma unroll
    for (int mi = 0; mi < 4; ++mi)
      #pragma unroll
      for (int nf = 0; nf < 2; ++nf)
        acc[mi][nf] = __builtin_amdgcn_mfma_f32_16x16x32_bf16(a[mi], b[nf], acc[mi][nf], 0, 0, 0);
  }
}

__device__ __forceinline__ void zero4(f32x4 acc[4][2]){
  #pragma unroll
  for (int mi = 0; mi < 4; ++mi)
    #pragma unroll
    for (int nf = 0; nf < 2; ++nf)
      acc[mi][nf] = splat4(0.0f);
}

// GLU epilogue: h[mi][nf], mi in {0,1} -> features (w+4*mi)*16 + lg*4
__device__ __forceinline__ void glu_epi4(const f32x4 acc[4][2], const float* __restrict__ shrow,
                                         int w, int lg, f32x4 h[2][2])
{
  #pragma unroll
  for (int mi = 0; mi < 2; ++mi) {
    const int f0 = (w + 4*mi)*16 + lg*4;
    const f32x4 bh = *(const f32x4*)(shrow + f0);
    const f32x4 bg = *(const f32x4*)(shrow + f0 + 128);
    #pragma unroll
    for (int nf = 0; nf < 2; ++nf)
      #pragma unroll
      for (int c = 0; c < 4; ++c) {
        float v = acc[mi][nf][c] + bh[c];
        float g = acc[mi+2][nf][c] + bg[c];
        h[mi][nf][c] = v * sigm(g);
      }
  }
}

// write this wave's 32 features of a 128-wide activation [32][128] bf16 (swizzled)
__device__ __forceinline__ void write_half(u16* dst, const f32x4 v[2][2], int w, int l15, int lg, int swzv)
{
  #pragma unroll
  for (int mi = 0; mi < 2; ++mi) {
    const int f0 = (w + 4*mi)*16 + lg*4;
    #pragma unroll
    for (int nf = 0; nf < 2; ++nf) {
      const int s = nf*16 + l15;
      uint2 p;
      p.x = pk2(v[mi][nf][0], v[mi][nf][1]);
      p.y = pk2(v[mi][nf][2], v[mi][nf][3]);
      *(uint2*)(dst + ((s*128 + f0) ^ swzv)) = p;
    }
  }
}

// shared_block + dep_block (invocation inv uses dep weights inv*2+{0,1})
// big layout (u16): h at [0:4096], x at [4096:8192]
__device__ __forceinline__ void shared_dep(const u16* __restrict__ pk, const float* __restrict__ shiftT,
                                           const u16* binput, u16* big, int inv,
                                           int w, int l15, int lg, int swzv, f32x4 xres[2][2])
{
  f32x4 acc[4][2];
  zero4(acc);
  gemm4<8, 256, 0>(pk + PK_G0_US, binput, w, l15, lg, swzv, acc);
  f32x4 h[2][2];
  glu_epi4(acc, shiftT + 0, w, lg, h);
  __syncthreads();                       // all waves done reading binput (may alias big)
  write_half(big, h, w, l15, lg, swzv);  // h -> big[0:4096]
  __syncthreads();

  zero4(acc);
  gemm4<4, 128, 0>(pk + PK_G1_US, big, w, l15, lg, swzv, acc);
  f32x4 h2[2][2];
  glu_epi4(acc, shiftT + 256, w, lg, h2);
  #pragma unroll
  for (int mi = 0; mi < 2; ++mi)
    #pragma unroll
    for (int nf = 0; nf < 2; ++nf)
      xres[mi][nf] = (h[mi][nf] + h2[mi][nf]) * SQRT_HALF;
  write_half(big + 4096, xres, w, l15, lg, swzv);   // x -> big[4096:8192]
  __syncthreads();

  #pragma unroll
  for (int i = 0; i < 2; ++i) {
    zero4(acc);
    gemm4<4, 128, 0>(pk + PK_DEP_US + (inv*2 + i)*32768, big + 4096, w, l15, lg, swzv, acc);
    f32x4 hd[2][2];
    glu_epi4(acc, shiftT + (2 + inv*2 + i)*256, w, lg, hd);
    __syncthreads();                     // all waves done reading x before in-place update
    #pragma unroll
    for (int mi = 0; mi < 2; ++mi)
      #pragma unroll
      for (int nf = 0; nf < 2; ++nf)
        xres[mi][nf] = (xres[mi][nf] + hd[mi][nf]) * SQRT_HALF;
    write_half(big + 4096, xres, w, l15, lg, swzv);
    __syncthreads();
  }
}

// ---------------- main fused kernel ----------------
// 32 samples/block, 4 waves (256 thr), LDS = 32 KiB -> 4 independent blocks/CU
// (VGPR 128 * 16 waves == full pool). Sparsemax reduction aliased on dead h-region.
__global__ void __launch_bounds__(256, 4)
tabnet_main(const float* __restrict__ inp, const u16* __restrict__ pk,
            const float* __restrict__ shiftT, const float* __restrict__ inSc,
            const float* __restrict__ inSh, float* __restrict__ out)
{
  __shared__ __align__(16) u16 feat[32*256];
  __shared__ __align__(16) u16 big[32*256];
  float2* red2 = (float2*)big;      // [buf*288 + si*9 + w], alias on dead h-region (<=4608B)

  const int tid  = threadIdx.x;
  const int w    = tid >> 6;        // 0..3
  const int lane = tid & 63;
  const int l15  = lane & 15, lg = lane >> 4;
  const int swzv = (l15 & 7) << 3;
  const long long row0 = (long long)blockIdx.x * 32;

  // stage 0: features = BN(inputs) -> feat (bf16, swizzled [sample][256])
  {
    const int f = lane*4;
    const f32x4 sc = *(const f32x4*)(inSc + f);
    const f32x4 sh = *(const f32x4*)(inSh + f);
    #pragma unroll
    for (int j = 0; j < 8; ++j) {
      const int s = j*4 + w;
      f32x4 v = *(const f32x4*)(inp + (row0 + s)*256 + f);
      uint2 p;
      p.x = pk2(v[0]*sc[0] + sh[0], v[1]*sc[1] + sh[1]);
      p.y = pk2(v[2]*sc[2] + sh[2], v[3]*sc[3] + sh[3]);
      *(uint2*)(feat + ((s*256 + f) ^ ((s & 7) << 3))) = p;
    }
  }
  __syncthreads();

  f32x4 xres[2][2];
  shared_dep(pk, shiftT, feat, big, 0, w, l15, lg, swzv, xres);

  __half2 priorH[4][2][2];       // prior packed f16 (pairs over c)
  f32x4 outAg[2];
  {
    const __half2 one2 = __float2half2_rn(1.0f);
    #pragma unroll
    for (int mi = 0; mi < 4; ++mi)
      #pragma unroll
      for (int nf = 0; nf < 2; ++nf) {
        priorH[mi][nf][0] = one2; priorH[mi][nf][1] = one2;
      }
    outAg[0] = splat4(0.0f); outAg[1] = splat4(0.0f);
  }

  #pragma unroll 1
  for (int st = 0; st < 3; ++st) {
    // attention: logits = BN(a @ at_W[st]) * prior, a = x[:,64:128] (big_x KOFF=64)
    f32x4 z[4][2];
    zero4(z);
    gemm4<2, 128, 64>(pk + PK_AT_US + st*16384, big + 4096, w, l15, lg, swzv, z);
    #pragma unroll
    for (int mi = 0; mi < 4; ++mi) {
      const f32x4 bz = *(const f32x4*)(shiftT + (10 + st)*256 + (w + 4*mi)*16 + lg*4);
      #pragma unroll
      for (int nf = 0; nf < 2; ++nf) {
        float2 p0 = __half22float2(priorH[mi][nf][0]);
        float2 p1 = __half22float2(priorH[mi][nf][1]);
        z[mi][nf][0] = (z[mi][nf][0] + bz[0]) * p0.x;
        z[mi][nf][1] = (z[mi][nf][1] + bz[1]) * p0.y;
        z[mi][nf][2] = (z[mi][nf][2] + bz[2]) * p1.x;
        z[mi][nf][3] = (z[mi][nf][3] + bz[3]) * p1.y;
      }
    }

    // ---- rowmax -> tau0 = max - 1 (red2 touches only big[0:4608] = dead h-region)
    float tau[2];
    {
      #pragma unroll
      for (int nf = 0; nf < 2; ++nf) {
        float m = -1e30f;
        #pragma unroll
        for (int mi = 0; mi < 4; ++mi)
          #pragma unroll
          for (int c = 0; c < 4; ++c) m = fmaxf(m, z[mi][nf][c]);
        m = fmaxf(m, __shfl_xor(m, 16, 64));
        m = fmaxf(m, __shfl_xor(m, 32, 64));
        if (lg == 0) { int si = nf*16 + l15; red2[si*9 + w].x = m; }
      }
      __syncthreads();
      #pragma unroll
      for (int nf = 0; nf < 2; ++nf) {
        const int si = nf*16 + l15;
        float m = fmaxf(fmaxf(red2[si*9+0].x, red2[si*9+1].x),
                        fmaxf(red2[si*9+2].x, red2[si*9+3].x));
        tau[nf] = m - 1.0f;
      }
    }

    // ---- Newton iterations, 1 barrier each, uniform early exit
    int buf = 0;
    #pragma unroll 1
    for (int it = 0; it < 12; ++it) {
      buf ^= 1;
      float S[2], C[2];
      #pragma unroll
      for (int nf = 0; nf < 2; ++nf) {
        f32x4 s4 = splat4(0.0f), c4 = splat4(0.0f);
        #pragma unroll
        for (int mi = 0; mi < 4; ++mi)
          #pragma unroll
          for (int c = 0; c < 4; ++c) {
            float d = z[mi][nf][c] - tau[nf];
            s4[c] += fmaxf(d, 0.0f);
            c4[c] += (d > 0.0f) ? 1.0f : 0.0f;
          }
        float S_ = (s4[0] + s4[1]) + (s4[2] + s4[3]);
        float C_ = (c4[0] + c4[1]) + (c4[2] + c4[3]);
        S_ += __shfl_xor(S_, 16, 64); S_ += __shfl_xor(S_, 32, 64);
        C_ += __shfl_xor(C_, 16, 64); C_ += __shfl_xor(C_, 32, 64);
        S[nf] = S_; C[nf] = C_;
      }
      if (lg == 0) {
        #pragma unroll
        for (int nf = 0; nf < 2; ++nf) {
          int si = nf*16 + l15;
          float2 p; p.x = S[nf]; p.y = C[nf];
          red2[buf*288 + si*9 + w] = p;
        }
      }
      __syncthreads();
      bool ok = true;
      float tauN[2];
      #pragma unroll
      for (int nf = 0; nf < 2; ++nf) {
        const int si = nf*16 + l15;
        float Ss = 0.0f, Cs = 0.0f;
        #pragma unroll
        for (int i = 0; i < 4; ++i) { float2 p = red2[buf*288 + si*9 + i]; Ss += p.x; Cs += p.y; }
        ok = ok && (fabsf(Ss - 1.0f) < 1e-5f);
        tauN[nf] = tau[nf] + (Ss - 1.0f) / Cs;
      }
      if (__all(ok)) break;
      #pragma unroll
      for (int nf = 0; nf < 2; ++nf) tau[nf] = tauN[nf];
    }
    __syncthreads();   // all waves done reading red2 before mask overwrites big

    // mask, prior update, masked = mask * features -> big (full [32][256])
    #pragma unroll
    for (int mi = 0; mi < 4; ++mi) {
      const int f0 = (w + 4*mi)*16 + lg*4;
      #pragma unroll
      for (int nf = 0; nf < 2; ++nf) {
        const int si = nf*16 + l15;
        ushort4 fv = *(const ushort4*)(feat + ((si*256 + f0) ^ swzv));
        float m0 = fmaxf(z[mi][nf][0] - tau[nf], 0.0f);
        float m1 = fmaxf(z[mi][nf][1] - tau[nf], 0.0f);
        float m2 = fmaxf(z[mi][nf][2] - tau[nf], 0.0f);
        float m3 = fmaxf(z[mi][nf][3] - tau[nf], 0.0f);
        float2 p0 = __half22float2(priorH[mi][nf][0]);
        float2 p1 = __half22float2(priorH[mi][nf][1]);
        p0.x *= (RELAX - m0); p0.y *= (RELAX - m1);
        p1.x *= (RELAX - m2); p1.y *= (RELAX - m3);
        priorH[mi][nf][0] = __floats2half2_rn(p0.x, p0.y);
        priorH[mi][nf][1] = __floats2half2_rn(p1.x, p1.y);
        uint2 p;
        p.x = pk2(bf2f(fv.x) * m0, bf2f(fv.y) * m1);
        p.y = pk2(bf2f(fv.z) * m2, bf2f(fv.w) * m3);
        *(uint2*)(big + ((si*256 + f0) ^ swzv)) = p;
      }
    }
    __syncthreads();   // masked visible before G0 reads

    shared_dep(pk, shiftT, big, big, st + 1, w, l15, lg, swzv, xres);

    // out_agg += relu(x[:, :64]); features 0..63 = value m-frag mi=0 of each wave
    #pragma unroll
    for (int nf = 0; nf < 2; ++nf)
      #pragma unroll
      for (int c = 0; c < 4; ++c)
        outAg[nf][c] += fmaxf(xres[0][nf][c], 0.0f);
  }

  // final: out = out_agg @ Wout, split-bf16 (hi/lo) for precision
  // stage agg into big[0:2048] hi, big[2048:4096] lo  ([32][64] bf16, swizzled)
  {
    #pragma unroll
    for (int nf = 0; nf < 2; ++nf) {
      const int si = nf*16 + l15;
      const int f0 = w*16 + lg*4;
      ushort4 hi, lo;
      u16 h0 = f2bf(outAg[nf][0]); hi.x = h0; lo.x = f2bf(outAg[nf][0] - bf2f(h0));
      u16 h1 = f2bf(outAg[nf][1]); hi.y = h1; lo.y = f2bf(outAg[nf][1] - bf2f(h1));
      u16 h2v = f2bf(outAg[nf][2]); hi.z = h2v; lo.z = f2bf(outAg[nf][2] - bf2f(h2v));
      u16 h3 = f2bf(outAg[nf][3]); hi.w = h3; lo.w = f2bf(outAg[nf][3] - bf2f(h3));
      *(ushort4*)(big + ((si*64 + f0) ^ swzv)) = hi;
      *(ushort4*)(big + 2048 + ((si*64 + f0) ^ swzv)) = lo;
    }
  }
  __syncthreads();

  // 64x64x(32 samples) GEMM: wave w -> out m-frag w, both sample n-frags
  {
    const int lane64 = lg*16 + l15;
    f32x4 facc[2];
    facc[0] = splat4(0.0f); facc[1] = splat4(0.0f);
    #pragma unroll
    for (int ks = 0; ks < 2; ++ks) {
      short8 aHi = *(const short8*)(pk + PK_WOUT_US   + (size_t)((w*2 + ks)*64 + lane64)*8);
      short8 aLo = *(const short8*)(pk + PK_WOUTLO_US + (size_t)((w*2 + ks)*64 + lane64)*8);
      #pragma unroll
      for (int j = 0; j < 2; ++j) {
        const int si = j*16 + l15;
        short8 bHi = *(const short8*)(big + ((si*64 + ks*32 + lg*8) ^ swzv));
        short8 bLo = *(const short8*)(big + 2048 + ((si*64 + ks*32 + lg*8) ^ swzv));
        facc[j] = __builtin_amdgcn_mfma_f32_16x16x32_bf16(aHi, bHi, facc[j], 0, 0, 0);
        facc[j] = __builtin_amdgcn_mfma_f32_16x16x32_bf16(aHi, bLo, facc[j], 0, 0, 0);
        facc[j] = __builtin_amdgcn_mfma_f32_16x16x32_bf16(aLo, bHi, facc[j], 0, 0, 0);
      }
    }
    #pragma unroll
    for (int j = 0; j < 2; ++j) {
      const int si = j*16 + l15;
      *(f32x4*)(out + (row0 + si)*64 + w*16 + lg*4) = facc[j];
    }
  }
}

// ---------------- launch ----------------
extern "C" void kernel_launch(void* const* d_in, const int* in_sizes, int n_in,
                              void* d_out, int out_size, void* d_ws, size_t ws_size,
                              hipStream_t stream)
{
  const float* inp   = (const float*)d_in[0];
  const float* in_g  = (const float*)d_in[1];
  const float* in_b  = (const float*)d_in[2];
  const float* in_m  = (const float*)d_in[3];
  const float* in_v  = (const float*)d_in[4];
  const float* sh_W0 = (const float*)d_in[5];
  const float* sh_W1 = (const float*)d_in[6];
  const float* sh_g  = (const float*)d_in[7];
  const float* sh_b  = (const float*)d_in[8];
  const float* sh_m  = (const float*)d_in[9];
  const float* sh_v  = (const float*)d_in[10];
  const float* dep_W = (const float*)d_in[11];
  const float* dep_g = (const float*)d_in[12];
  const float* dep_b = (const float*)d_in[13];
  const float* dep_m = (const float*)d_in[14];
  const float* dep_v = (const float*)d_in[15];
  const float* at_W  = (const float*)d_in[16];
  const float* at_g  = (const float*)d_in[17];
  const float* at_b  = (const float*)d_in[18];
  const float* at_m  = (const float*)d_in[19];
  const float* at_v  = (const float*)d_in[20];
  const float* Wout  = (const float*)d_in[21];

  unsigned char* ws = (unsigned char*)d_ws;
  u16*   pk     = (u16*)ws;
  float* shiftT = (float*)(ws + OFF_SHIFT);
  float* scaleT = (float*)(ws + OFF_SCALE);
  float* inSc   = (float*)(ws + OFF_INSC);
  float* inSh   = (float*)(ws + OFF_INSH);

  hipLaunchKernelGGL(prep_bn, dim3(14), dim3(256), 0, stream,
                     in_g, in_b, in_m, in_v, sh_g, sh_b, sh_m, sh_v,
                     dep_g, dep_b, dep_m, dep_v, at_g, at_b, at_m, at_v,
                     shiftT, scaleT, inSc, inSh);
  hipLaunchKernelGGL(prep_pack, dim3(204), dim3(256), 0, stream,
                     sh_W0, sh_W1, dep_W, at_W, Wout, scaleT, pk);
  hipLaunchKernelGGL(tabnet_main, dim3(4096), dim3(256), 0, stream,
                     inp, pk, shiftT, inSc, inSh, (float*)d_out);
}

// Round 7
// 768.145 us; speedup vs baseline: 1.2168x; 1.2168x over previous
//
#include <hip/hip_runtime.h>
#include <hip/hip_bf16.h>
#include <hip/hip_fp16.h>

typedef unsigned short u16;
typedef __attribute__((ext_vector_type(8))) short short8;
typedef __attribute__((ext_vector_type(4))) float f32x4;

#define BN_EPS    1e-3f
#define RELAX     1.3f
#define SQRT_HALF 0.7071067811865476f

// packed-weight offsets (ushort units)
#define PK_G0_US     0
#define PK_G1_US     65536
#define PK_DEP_US    98304
#define PK_AT_US     360448
#define PK_WOUT_US   409600
#define PK_WOUTLO_US 413696
// ws byte offsets
#define OFF_SHIFT 835584
#define OFF_SCALE 848896
#define OFF_INSC  862208
#define OFF_INSH  863232

__device__ __forceinline__ u16 f2bf(float x){
  unsigned u = __float_as_uint(x);
  return (u16)((u + 0x7fffu + ((u >> 16) & 1u)) >> 16);
}
__device__ __forceinline__ float bf2f(u16 h){ return __uint_as_float(((unsigned)h) << 16); }
__device__ __forceinline__ float sigm(float x){ return 1.0f / (1.0f + __expf(-x)); }
__device__ __forceinline__ f32x4 splat4(float x){ f32x4 v; v[0]=x; v[1]=x; v[2]=x; v[3]=x; return v; }

// packed pair f32->bf16 (RTNE) -> one u32 (v_cvt_pk_bf16_f32)
__device__ __forceinline__ unsigned pk2(float a, float b){
  float2 t; t.x = a; t.y = b;
  union { __hip_bfloat162 h; unsigned u; } v;
  v.h = __float22bfloat162_rn(t);
  return v.u;
}

// ---------------- prep: BN scale/shift tables ----------------
__global__ void prep_bn(
  const float* in_g, const float* in_b, const float* in_m, const float* in_v,
  const float* sh_g, const float* sh_b, const float* sh_m, const float* sh_v,
  const float* dep_g, const float* dep_b, const float* dep_m, const float* dep_v,
  const float* at_g, const float* at_b, const float* at_m, const float* at_v,
  float* shiftT, float* scaleT, float* inSc, float* inSh)
{
  int r = blockIdx.x, f = threadIdx.x;
  if (r < 13) {
    const float *g, *bb, *mm, *vv;
    if (r < 2)       { g = sh_g + r*256;        bb = sh_b + r*256;        mm = sh_m + r*256;        vv = sh_v + r*256; }
    else if (r < 10) { int j = r-2;  g = dep_g + j*256; bb = dep_b + j*256; mm = dep_m + j*256; vv = dep_v + j*256; }
    else             { int j = r-10; g = at_g  + j*256; bb = at_b  + j*256; mm = at_m  + j*256; vv = at_v  + j*256; }
    float sc = g[f] * rsqrtf(vv[f] + BN_EPS);
    scaleT[r*256 + f] = sc;
    shiftT[r*256 + f] = bb[f] - mm[f]*sc;
  } else {
    float sc = in_g[f] * rsqrtf(in_v[f] + BN_EPS);
    inSc[f] = sc;
    inSh[f] = in_b[f] - in_m[f]*sc;
  }
}

// ---------------- prep: pack weights into MFMA A-fragment order (BN scale folded) ----------------
__global__ void prep_pack(
  const float* sh_W0, const float* sh_W1, const float* dep_W,
  const float* at_W, const float* Wout, const float* scaleT, u16* pk)
{
  int c = blockIdx.x*256 + threadIdx.x;   // 16B chunk id, 0..52223
  const float* W; int K, Nout, srow, base; bool lo = false;
  if (c < 8192)       { W = sh_W0; K = 256; Nout = 256; srow = 0;  base = 0; }
  else if (c < 12288) { W = sh_W1; K = 128; Nout = 256; srow = 1;  base = 8192; }
  else if (c < 45056) { int j = (c-12288) >> 12; W = dep_W + j*32768; K = 128; Nout = 256; srow = 2+j;  base = 12288 + j*4096; }
  else if (c < 51200) { int j = (c-45056) >> 11; W = at_W  + j*16384; K = 64;  Nout = 256; srow = 10+j; base = 45056 + j*2048; }
  else if (c < 51712) { W = Wout; K = 64; Nout = 64; srow = -1; base = 51200; }
  else                { W = Wout; K = 64; Nout = 64; srow = -1; base = 51712; lo = true; }
  int local = c - base;
  int lane  = local & 63;
  int t     = local >> 6;
  int KS    = K >> 5;
  int lsh   = (K == 256) ? 3 : (K == 128) ? 2 : 1;
  int ks    = t & (KS - 1);
  int mf    = t >> lsh;
  int feat  = mf*16 + (lane & 15);
  int k0    = ks*32 + ((lane >> 4) << 3);
  float scl = (srow < 0) ? 1.0f : scaleT[srow*256 + feat];
  u16 v[8];
  #pragma unroll
  for (int j = 0; j < 8; ++j) {
    float x = W[(size_t)(k0 + j)*Nout + feat] * scl;
    u16 h = f2bf(x);
    if (lo) h = f2bf(x - bf2f(h));
    v[j] = h;
  }
  ushort4* d4 = (ushort4*)(pk + (size_t)c*8);
  ushort4 p0; p0.x=v[0]; p0.y=v[1]; p0.z=v[2]; p0.w=v[3];
  ushort4 p1; p1.x=v[4]; p1.y=v[5]; p1.z=v[6]; p1.w=v[7];
  d4[0] = p0; d4[1] = p1;
}

// ---------------- main fused kernel helpers (4 waves, 4 m-frags/wave, 2 n-frags) ----------------
// wave w owns m-frags {w, w+4, w+8, w+12}; value cols = mi 0,1 (frags w,w+4),
// gate cols = mi 2,3 (frags w+8,w+12). n-frags cover 32 samples.
template<int KS, int LDB, int KOFF>
__device__ __forceinline__ void gemm4(const u16* __restrict__ pk, const u16* bufB,
                                      int w, int l15, int lg, int swzv, f32x4 acc[4][2])
{
  const int lane = lg*16 + l15;
  #pragma unroll 2
  for (int ks = 0; ks < KS; ++ks) {
    short8 b[2];
    #pragma unroll
    for (int nf = 0; nf < 2; ++nf) {
      int idx = (nf*16 + l15)*LDB + KOFF + ks*32 + lg*8;
      b[nf] = *(const short8*)(bufB + (idx ^ swzv));
    }
    short8 a[4];
    #pragma unroll
    for (int mi = 0; mi < 4; ++mi)
      a[mi] = *(const short8*)(pk + (size_t)(((w + 4*mi)*KS + ks)*64 + lane)*8);
    #pragma unroll
    for (int mi = 0; mi < 4; ++mi)
      #pragma unroll
      for (int nf = 0; nf < 2; ++nf)
        acc[mi][nf] = __builtin_amdgcn_mfma_f32_16x16x32_bf16(a[mi], b[nf], acc[mi][nf], 0, 0, 0);
  }
}

__device__ __forceinline__ void zero4(f32x4 acc[4][2]){
  #pragma unroll
  for (int mi = 0; mi < 4; ++mi)
    #pragma unroll
    for (int nf = 0; nf < 2; ++nf)
      acc[mi][nf] = splat4(0.0f);
}

// GLU epilogue: h[mi][nf], mi in {0,1} -> features (w+4*mi)*16 + lg*4
__device__ __forceinline__ void glu_epi4(const f32x4 acc[4][2], const float* __restrict__ shrow,
                                         int w, int lg, f32x4 h[2][2])
{
  #pragma unroll
  for (int mi = 0; mi < 2; ++mi) {
    const int f0 = (w + 4*mi)*16 + lg*4;
    const f32x4 bh = *(const f32x4*)(shrow + f0);
    const f32x4 bg = *(const f32x4*)(shrow + f0 + 128);
    #pragma unroll
    for (int nf = 0; nf < 2; ++nf)
      #pragma unroll
      for (int c = 0; c < 4; ++c) {
        float v = acc[mi][nf][c] + bh[c];
        float g = acc[mi+2][nf][c] + bg[c];
        h[mi][nf][c] = v * sigm(g);
      }
  }
}

// write this wave's 32 features of a 128-wide activation [32][128] bf16 (swizzled)
__device__ __forceinline__ void write_half(u16* dst, const f32x4 v[2][2], int w, int l15, int lg, int swzv)
{
  #pragma unroll
  for (int mi = 0; mi < 2; ++mi) {
    const int f0 = (w + 4*mi)*16 + lg*4;
    #pragma unroll
    for (int nf = 0; nf < 2; ++nf) {
      const int s = nf*16 + l15;
      uint2 p;
      p.x = pk2(v[mi][nf][0], v[mi][nf][1]);
      p.y = pk2(v[mi][nf][2], v[mi][nf][3]);
      *(uint2*)(dst + ((s*128 + f0) ^ swzv)) = p;
    }
  }
}

// shared_block + dep_block (invocation inv uses dep weights inv*2+{0,1})
// big layout (u16): h at [0:4096], x at [4096:8192]
__device__ __forceinline__ void shared_dep(const u16* __restrict__ pk, const float* __restrict__ shiftT,
                                           const u16* binput, u16* big, int inv,
                                           int w, int l15, int lg, int swzv, f32x4 xres[2][2])
{
  f32x4 acc[4][2];
  zero4(acc);
  gemm4<8, 256, 0>(pk + PK_G0_US, binput, w, l15, lg, swzv, acc);
  f32x4 h[2][2];
  glu_epi4(acc, shiftT + 0, w, lg, h);
  __syncthreads();                       // all waves done reading binput (may alias big)
  write_half(big, h, w, l15, lg, swzv);  // h -> big[0:4096]
  __syncthreads();

  zero4(acc);
  gemm4<4, 128, 0>(pk + PK_G1_US, big, w, l15, lg, swzv, acc);
  f32x4 h2[2][2];
  glu_epi4(acc, shiftT + 256, w, lg, h2);
  #pragma unroll
  for (int mi = 0; mi < 2; ++mi)
    #pragma unroll
    for (int nf = 0; nf < 2; ++nf)
      xres[mi][nf] = (h[mi][nf] + h2[mi][nf]) * SQRT_HALF;
  write_half(big + 4096, xres, w, l15, lg, swzv);   // x -> big[4096:8192]
  __syncthreads();

  #pragma unroll
  for (int i = 0; i < 2; ++i) {
    zero4(acc);
    gemm4<4, 128, 0>(pk + PK_DEP_US + (inv*2 + i)*32768, big + 4096, w, l15, lg, swzv, acc);
    f32x4 hd[2][2];
    glu_epi4(acc, shiftT + (2 + inv*2 + i)*256, w, lg, hd);
    __syncthreads();                     // all waves done reading x before in-place update
    #pragma unroll
    for (int mi = 0; mi < 2; ++mi)
      #pragma unroll
      for (int nf = 0; nf < 2; ++nf)
        xres[mi][nf] = (xres[mi][nf] + hd[mi][nf]) * SQRT_HALF;
    write_half(big + 4096, xres, w, l15, lg, swzv);
    __syncthreads();
  }
}

// ---------------- main fused kernel ----------------
// 32 samples/block, 4 waves (256 thr), LDS = 32 KiB -> 4 independent blocks/CU.
// __launch_bounds__(256,2): empirically hipcc caps VGPR at ~256/arg2 -> 128,
// which this kernel fits without spilling (proven in r2/r4/r5).
__global__ void __launch_bounds__(256, 2)
tabnet_main(const float* __restrict__ inp, const u16* __restrict__ pk,
            const float* __restrict__ shiftT, const float* __restrict__ inSc,
            const float* __restrict__ inSh, float* __restrict__ out)
{
  __shared__ __align__(16) u16 feat[32*256];
  __shared__ __align__(16) u16 big[32*256];
  float2* red2 = (float2*)big;      // [buf*288 + si*9 + w], alias on dead h-region (<=4608B)

  const int tid  = threadIdx.x;
  const int w    = tid >> 6;        // 0..3
  const int lane = tid & 63;
  const int l15  = lane & 15, lg = lane >> 4;
  const int swzv = (l15 & 7) << 3;
  const long long row0 = (long long)blockIdx.x * 32;

  // stage 0: features = BN(inputs) -> feat (bf16, swizzled [sample][256])
  {
    const int f = lane*4;
    const f32x4 sc = *(const f32x4*)(inSc + f);
    const f32x4 sh = *(const f32x4*)(inSh + f);
    #pragma unroll
    for (int j = 0; j < 8; ++j) {
      const int s = j*4 + w;
      f32x4 v = *(const f32x4*)(inp + (row0 + s)*256 + f);
      uint2 p;
      p.x = pk2(v[0]*sc[0] + sh[0], v[1]*sc[1] + sh[1]);
      p.y = pk2(v[2]*sc[2] + sh[2], v[3]*sc[3] + sh[3]);
      *(uint2*)(feat + ((s*256 + f) ^ ((s & 7) << 3))) = p;
    }
  }
  __syncthreads();

  f32x4 xres[2][2];
  shared_dep(pk, shiftT, feat, big, 0, w, l15, lg, swzv, xres);

  __half2 priorH[4][2][2];       // prior packed f16 (pairs over c)
  f32x4 outAg[2];
  {
    const __half2 one2 = __float2half2_rn(1.0f);
    #pragma unroll
    for (int mi = 0; mi < 4; ++mi)
      #pragma unroll
      for (int nf = 0; nf < 2; ++nf) {
        priorH[mi][nf][0] = one2; priorH[mi][nf][1] = one2;
      }
    outAg[0] = splat4(0.0f); outAg[1] = splat4(0.0f);
  }

  #pragma unroll 1
  for (int st = 0; st < 3; ++st) {
    // attention: logits = BN(a @ at_W[st]) * prior, a = x[:,64:128] (big_x KOFF=64)
    f32x4 z[4][2];
    zero4(z);
    gemm4<2, 128, 64>(pk + PK_AT_US + st*16384, big + 4096, w, l15, lg, swzv, z);
    #pragma unroll
    for (int mi = 0; mi < 4; ++mi) {
      const f32x4 bz = *(const f32x4*)(shiftT + (10 + st)*256 + (w + 4*mi)*16 + lg*4);
      #pragma unroll
      for (int nf = 0; nf < 2; ++nf) {
        float2 p0 = __half22float2(priorH[mi][nf][0]);
        float2 p1 = __half22float2(priorH[mi][nf][1]);
        z[mi][nf][0] = (z[mi][nf][0] + bz[0]) * p0.x;
        z[mi][nf][1] = (z[mi][nf][1] + bz[1]) * p0.y;
        z[mi][nf][2] = (z[mi][nf][2] + bz[2]) * p1.x;
        z[mi][nf][3] = (z[mi][nf][3] + bz[3]) * p1.y;
      }
    }

    // ---- rowmax -> tau0 = max - 1 (red2 touches only big[0:4608] = dead h-region)
    float tau[2];
    {
      #pragma unroll
      for (int nf = 0; nf < 2; ++nf) {
        float m = -1e30f;
        #pragma unroll
        for (int mi = 0; mi < 4; ++mi)
          #pragma unroll
          for (int c = 0; c < 4; ++c) m = fmaxf(m, z[mi][nf][c]);
        m = fmaxf(m, __shfl_xor(m, 16, 64));
        m = fmaxf(m, __shfl_xor(m, 32, 64));
        if (lg == 0) { int si = nf*16 + l15; red2[si*9 + w].x = m; }
      }
      __syncthreads();
      #pragma unroll
      for (int nf = 0; nf < 2; ++nf) {
        const int si = nf*16 + l15;
        float m = fmaxf(fmaxf(red2[si*9+0].x, red2[si*9+1].x),
                        fmaxf(red2[si*9+2].x, red2[si*9+3].x));
        tau[nf] = m - 1.0f;
      }
    }

    // ---- Newton iterations, 1 barrier each, uniform early exit
    int buf = 0;
    #pragma unroll 1
    for (int it = 0; it < 12; ++it) {
      buf ^= 1;
      float S[2], C[2];
      #pragma unroll
      for (int nf = 0; nf < 2; ++nf) {
        f32x4 s4 = splat4(0.0f), c4 = splat4(0.0f);
        #pragma unroll
        for (int mi = 0; mi < 4; ++mi)
          #pragma unroll
          for (int c = 0; c < 4; ++c) {
            float d = z[mi][nf][c] - tau[nf];
            s4[c] += fmaxf(d, 0.0f);
            c4[c] += (d > 0.0f) ? 1.0f : 0.0f;
          }
        float S_ = (s4[0] + s4[1]) + (s4[2] + s4[3]);
        float C_ = (c4[0] + c4[1]) + (c4[2] + c4[3]);
        S_ += __shfl_xor(S_, 16, 64); S_ += __shfl_xor(S_, 32, 64);
        C_ += __shfl_xor(C_, 16, 64); C_ += __shfl_xor(C_, 32, 64);
        S[nf] = S_; C[nf] = C_;
      }
      if (lg == 0) {
        #pragma unroll
        for (int nf = 0; nf < 2; ++nf) {
          int si = nf*16 + l15;
          float2 p; p.x = S[nf]; p.y = C[nf];
          red2[buf*288 + si*9 + w] = p;
        }
      }
      __syncthreads();
      bool ok = true;
      float tauN[2];
      #pragma unroll
      for (int nf = 0; nf < 2; ++nf) {
        const int si = nf*16 + l15;
        float Ss = 0.0f, Cs = 0.0f;
        #pragma unroll
        for (int i = 0; i < 4; ++i) { float2 p = red2[buf*288 + si*9 + i]; Ss += p.x; Cs += p.y; }
        ok = ok && (fabsf(Ss - 1.0f) < 1e-5f);
        tauN[nf] = tau[nf] + (Ss - 1.0f) / Cs;
      }
      if (__all(ok)) break;
      #pragma unroll
      for (int nf = 0; nf < 2; ++nf) tau[nf] = tauN[nf];
    }
    __syncthreads();   // all waves done reading red2 before mask overwrites big

    // mask, prior update, masked = mask * features -> big (full [32][256])
    #pragma unroll
    for (int mi = 0; mi < 4; ++mi) {
      const int f0 = (w + 4*mi)*16 + lg*4;
      #pragma unroll
      for (int nf = 0; nf < 2; ++nf) {
        const int si = nf*16 + l15;
        ushort4 fv = *(const ushort4*)(feat + ((si*256 + f0) ^ swzv));
        float m0 = fmaxf(z[mi][nf][0] - tau[nf], 0.0f);
        float m1 = fmaxf(z[mi][nf][1] - tau[nf], 0.0f);
        float m2 = fmaxf(z[mi][nf][2] - tau[nf], 0.0f);
        float m3 = fmaxf(z[mi][nf][3] - tau[nf], 0.0f);
        float2 p0 = __half22float2(priorH[mi][nf][0]);
        float2 p1 = __half22float2(priorH[mi][nf][1]);
        p0.x *= (RELAX - m0); p0.y *= (RELAX - m1);
        p1.x *= (RELAX - m2); p1.y *= (RELAX - m3);
        priorH[mi][nf][0] = __floats2half2_rn(p0.x, p0.y);
        priorH[mi][nf][1] = __floats2half2_rn(p1.x, p1.y);
        uint2 p;
        p.x = pk2(bf2f(fv.x) * m0, bf2f(fv.y) * m1);
        p.y = pk2(bf2f(fv.z) * m2, bf2f(fv.w) * m3);
        *(uint2*)(big + ((si*256 + f0) ^ swzv)) = p;
      }
    }
    __syncthreads();   // masked visible before G0 reads

    shared_dep(pk, shiftT, big, big, st + 1, w, l15, lg, swzv, xres);

    // out_agg += relu(x[:, :64]); features 0..63 = value m-frag mi=0 of each wave
    #pragma unroll
    for (int nf = 0; nf < 2; ++nf)
      #pragma unroll
      for (int c = 0; c < 4; ++c)
        outAg[nf][c] += fmaxf(xres[0][nf][c], 0.0f);
  }

  // final: out = out_agg @ Wout, split-bf16 (hi/lo) for precision
  // stage agg into big[0:2048] hi, big[2048:4096] lo  ([32][64] bf16, swizzled)
  {
    #pragma unroll
    for (int nf = 0; nf < 2; ++nf) {
      const int si = nf*16 + l15;
      const int f0 = w*16 + lg*4;
      ushort4 hi, lo;
      u16 h0 = f2bf(outAg[nf][0]); hi.x = h0; lo.x = f2bf(outAg[nf][0] - bf2f(h0));
      u16 h1 = f2bf(outAg[nf][1]); hi.y = h1; lo.y = f2bf(outAg[nf][1] - bf2f(h1));
      u16 h2v = f2bf(outAg[nf][2]); hi.z = h2v; lo.z = f2bf(outAg[nf][2] - bf2f(h2v));
      u16 h3 = f2bf(outAg[nf][3]); hi.w = h3; lo.w = f2bf(outAg[nf][3] - bf2f(h3));
      *(ushort4*)(big + ((si*64 + f0) ^ swzv)) = hi;
      *(ushort4*)(big + 2048 + ((si*64 + f0) ^ swzv)) = lo;
    }
  }
  __syncthreads();

  // 64x64x(32 samples) GEMM: wave w -> out m-frag w, both sample n-frags
  {
    const int lane64 = lg*16 + l15;
    f32x4 facc[2];
    facc[0] = splat4(0.0f); facc[1] = splat4(0.0f);
    #pragma unroll
    for (int ks = 0; ks < 2; ++ks) {
      short8 aHi = *(const short8*)(pk + PK_WOUT_US   + (size_t)((w*2 + ks)*64 + lane64)*8);
      short8 aLo = *(const short8*)(pk + PK_WOUTLO_US + (size_t)((w*2 + ks)*64 + lane64)*8);
      #pragma unroll
      for (int j = 0; j < 2; ++j) {
        const int si = j*16 + l15;
        short8 bHi = *(const short8*)(big + ((si*64 + ks*32 + lg*8) ^ swzv));
        short8 bLo = *(const short8*)(big + 2048 + ((si*64 + ks*32 + lg*8) ^ swzv));
        facc[j] = __builtin_amdgcn_mfma_f32_16x16x32_bf16(aHi, bHi, facc[j], 0, 0, 0);
        facc[j] = __builtin_amdgcn_mfma_f32_16x16x32_bf16(aHi, bLo, facc[j], 0, 0, 0);
        facc[j] = __builtin_amdgcn_mfma_f32_16x16x32_bf16(aLo, bHi, facc[j], 0, 0, 0);
      }
    }
    #pragma unroll
    for (int j = 0; j < 2; ++j) {
      const int si = j*16 + l15;
      *(f32x4*)(out + (row0 + si)*64 + w*16 + lg*4) = facc[j];
    }
  }
}

// ---------------- launch ----------------
extern "C" void kernel_launch(void* const* d_in, const int* in_sizes, int n_in,
                              void* d_out, int out_size, void* d_ws, size_t ws_size,
                              hipStream_t stream)
{
  const float* inp   = (const float*)d_in[0];
  const float* in_g  = (const float*)d_in[1];
  const float* in_b  = (const float*)d_in[2];
  const float* in_m  = (const float*)d_in[3];
  const float* in_v  = (const float*)d_in[4];
  const float* sh_W0 = (const float*)d_in[5];
  const float* sh_W1 = (const float*)d_in[6];
  const float* sh_g  = (const float*)d_in[7];
  const float* sh_b  = (const float*)d_in[8];
  const float* sh_m  = (const float*)d_in[9];
  const float* sh_v  = (const float*)d_in[10];
  const float* dep_W = (const float*)d_in[11];
  const float* dep_g = (const float*)d_in[12];
  const float* dep_b = (const float*)d_in[13];
  const float* dep_m = (const float*)d_in[14];
  const float* dep_v = (const float*)d_in[15];
  const float* at_W  = (const float*)d_in[16];
  const float* at_g  = (const float*)d_in[17];
  const float* at_b  = (const float*)d_in[18];
  const float* at_m  = (const float*)d_in[19];
  const float* at_v  = (const float*)d_in[20];
  const float* Wout  = (const float*)d_in[21];

  unsigned char* ws = (unsigned char*)d_ws;
  u16*   pk     = (u16*)ws;
  float* shiftT = (float*)(ws + OFF_SHIFT);
  float* scaleT = (float*)(ws + OFF_SCALE);
  float* inSc   = (float*)(ws + OFF_INSC);
  float* inSh   = (float*)(ws + OFF_INSH);

  hipLaunchKernelGGL(prep_bn, dim3(14), dim3(256), 0, stream,
                     in_g, in_b, in_m, in_v, sh_g, sh_b, sh_m, sh_v,
                     dep_g, dep_b, dep_m, dep_v, at_g, at_b, at_m, at_v,
                     shiftT, scaleT, inSc, inSh);
  hipLaunchKernelGGL(prep_pack, dim3(204), dim3(256), 0, stream,
                     sh_W0, sh_W1, dep_W, at_W, Wout, scaleT, pk);
  hipLaunchKernelGGL(tabnet_main, dim3(4096), dim3(256), 0, stream,
                     inp, pk, shiftT, inSc, inSh, (float*)d_out);
}

// Round 8
// 766.368 us; speedup vs baseline: 1.2196x; 1.0023x over previous
//
#include <hip/hip_runtime.h>
#include <hip/hip_bf16.h>
#include <hip/hip_fp16.h>

typedef unsigned short u16;
typedef __attribute__((ext_vector_type(8))) short short8;
typedef __attribute__((ext_vector_type(4))) float f32x4;

#define BN_EPS    1e-3f
#define RELAX     1.3f
#define SQRT_HALF 0.7071067811865476f

// packed-weight offsets (ushort units)
#define PK_G0_US     0
#define PK_G1_US     65536
#define PK_DEP_US    98304
#define PK_AT_US     360448
#define PK_WOUT_US   409600
#define PK_WOUTLO_US 413696
// ws byte offsets
#define OFF_SHIFT 835584
#define OFF_SCALE 848896
#define OFF_INSC  862208
#define OFF_INSH  863232

__device__ __forceinline__ u16 f2bf(float x){
  unsigned u = __float_as_uint(x);
  return (u16)((u + 0x7fffu + ((u >> 16) & 1u)) >> 16);
}
__device__ __forceinline__ float bf2f(u16 h){ return __uint_as_float(((unsigned)h) << 16); }
__device__ __forceinline__ float sigm(float x){ return 1.0f / (1.0f + __expf(-x)); }
__device__ __forceinline__ f32x4 splat4(float x){ f32x4 v; v[0]=x; v[1]=x; v[2]=x; v[3]=x; return v; }

// packed pair f32->bf16 (RTNE) -> one u32 (v_cvt_pk_bf16_f32)
__device__ __forceinline__ unsigned pk2(float a, float b){
  float2 t; t.x = a; t.y = b;
  union { __hip_bfloat162 h; unsigned u; } v;
  v.h = __float22bfloat162_rn(t);
  return v.u;
}
// unpack uint2 (4 bf16, pk2 order) -> f32x4: 2 shifts + 2 ands
__device__ __forceinline__ f32x4 unpk4(uint2 p){
  f32x4 r;
  r[0] = __uint_as_float(p.x << 16);
  r[1] = __uint_as_float(p.x & 0xffff0000u);
  r[2] = __uint_as_float(p.y << 16);
  r[3] = __uint_as_float(p.y & 0xffff0000u);
  return r;
}

// ---------------- prep: BN scale/shift tables ----------------
__global__ void prep_bn(
  const float* in_g, const float* in_b, const float* in_m, const float* in_v,
  const float* sh_g, const float* sh_b, const float* sh_m, const float* sh_v,
  const float* dep_g, const float* dep_b, const float* dep_m, const float* dep_v,
  const float* at_g, const float* at_b, const float* at_m, const float* at_v,
  float* shiftT, float* scaleT, float* inSc, float* inSh)
{
  int r = blockIdx.x, f = threadIdx.x;
  if (r < 13) {
    const float *g, *bb, *mm, *vv;
    if (r < 2)       { g = sh_g + r*256;        bb = sh_b + r*256;        mm = sh_m + r*256;        vv = sh_v + r*256; }
    else if (r < 10) { int j = r-2;  g = dep_g + j*256; bb = dep_b + j*256; mm = dep_m + j*256; vv = dep_v + j*256; }
    else             { int j = r-10; g = at_g  + j*256; bb = at_b  + j*256; mm = at_m  + j*256; vv = at_v  + j*256; }
    float sc = g[f] * rsqrtf(vv[f] + BN_EPS);
    scaleT[r*256 + f] = sc;
    shiftT[r*256 + f] = bb[f] - mm[f]*sc;
  } else {
    float sc = in_g[f] * rsqrtf(in_v[f] + BN_EPS);
    inSc[f] = sc;
    inSh[f] = in_b[f] - in_m[f]*sc;
  }
}

// ---------------- prep: pack weights into MFMA A-fragment order (BN scale folded) ----------------
__global__ void prep_pack(
  const float* sh_W0, const float* sh_W1, const float* dep_W,
  const float* at_W, const float* Wout, const float* scaleT, u16* pk)
{
  int c = blockIdx.x*256 + threadIdx.x;   // 16B chunk id, 0..52223
  const float* W; int K, Nout, srow, base; bool lo = false;
  if (c < 8192)       { W = sh_W0; K = 256; Nout = 256; srow = 0;  base = 0; }
  else if (c < 12288) { W = sh_W1; K = 128; Nout = 256; srow = 1;  base = 8192; }
  else if (c < 45056) { int j = (c-12288) >> 12; W = dep_W + j*32768; K = 128; Nout = 256; srow = 2+j;  base = 12288 + j*4096; }
  else if (c < 51200) { int j = (c-45056) >> 11; W = at_W  + j*16384; K = 64;  Nout = 256; srow = 10+j; base = 45056 + j*2048; }
  else if (c < 51712) { W = Wout; K = 64; Nout = 64; srow = -1; base = 51200; }
  else                { W = Wout; K = 64; Nout = 64; srow = -1; base = 51712; lo = true; }
  int local = c - base;
  int lane  = local & 63;
  int t     = local >> 6;
  int KS    = K >> 5;
  int lsh   = (K == 256) ? 3 : (K == 128) ? 2 : 1;
  int ks    = t & (KS - 1);
  int mf    = t >> lsh;
  int feat  = mf*16 + (lane & 15);
  int k0    = ks*32 + ((lane >> 4) << 3);
  float scl = (srow < 0) ? 1.0f : scaleT[srow*256 + feat];
  u16 v[8];
  #pragma unroll
  for (int j = 0; j < 8; ++j) {
    float x = W[(size_t)(k0 + j)*Nout + feat] * scl;
    u16 h = f2bf(x);
    if (lo) h = f2bf(x - bf2f(h));
    v[j] = h;
  }
  ushort4* d4 = (ushort4*)(pk + (size_t)c*8);
  ushort4 p0; p0.x=v[0]; p0.y=v[1]; p0.z=v[2]; p0.w=v[3];
  ushort4 p1; p1.x=v[4]; p1.y=v[5]; p1.z=v[6]; p1.w=v[7];
  d4[0] = p0; d4[1] = p1;
}

// ---------------- main fused kernel helpers (4 waves, 4 m-frags/wave, 2 n-frags) ----------------
// wave w owns m-frags {w, w+4, w+8, w+12}; value cols = mi 0,1 (frags w,w+4),
// gate cols = mi 2,3 (frags w+8,w+12). n-frags cover 32 samples.
template<int KS, int LDB, int KOFF>
__device__ __forceinline__ void gemm4(const u16* __restrict__ pk, const u16* bufB,
                                      int w, int l15, int lg, int swzv, f32x4 acc[4][2])
{
  const int lane = lg*16 + l15;
  #pragma unroll 2
  for (int ks = 0; ks < KS; ++ks) {
    short8 b[2];
    #pragma unroll
    for (int nf = 0; nf < 2; ++nf) {
      int idx = (nf*16 + l15)*LDB + KOFF + ks*32 + lg*8;
      b[nf] = *(const short8*)(bufB + (idx ^ swzv));
    }
    short8 a[4];
    #pragma unroll
    for (int mi = 0; mi < 4; ++mi)
      a[mi] = *(const short8*)(pk + (size_t)(((w + 4*mi)*KS + ks)*64 + lane)*8);
    #pragma unroll
    for (int mi = 0; mi < 4; ++mi)
      #pragma unroll
      for (int nf = 0; nf < 2; ++nf)
        acc[mi][nf] = __builtin_amdgcn_mfma_f32_16x16x32_bf16(a[mi], b[nf], acc[mi][nf], 0, 0, 0);
  }
}

__device__ __forceinline__ void zero4(f32x4 acc[4][2]){
  #pragma unroll
  for (int mi = 0; mi < 4; ++mi)
    #pragma unroll
    for (int nf = 0; nf < 2; ++nf)
      acc[mi][nf] = splat4(0.0f);
}

// GLU epilogue: h[mi][nf], mi in {0,1} -> features (w+4*mi)*16 + lg*4
__device__ __forceinline__ void glu_epi4(const f32x4 acc[4][2], const float* __restrict__ shrow,
                                         int w, int lg, f32x4 h[2][2])
{
  #pragma unroll
  for (int mi = 0; mi < 2; ++mi) {
    const int f0 = (w + 4*mi)*16 + lg*4;
    const f32x4 bh = *(const f32x4*)(shrow + f0);
    const f32x4 bg = *(const f32x4*)(shrow + f0 + 128);
    #pragma unroll
    for (int nf = 0; nf < 2; ++nf)
      #pragma unroll
      for (int c = 0; c < 4; ++c) {
        float v = acc[mi][nf][c] + bh[c];
        float g = acc[mi+2][nf][c] + bg[c];
        h[mi][nf][c] = v * sigm(g);
      }
  }
}

// write this wave's 32 features of a 128-wide activation [32][128] bf16 (swizzled)
__device__ __forceinline__ void write_half(u16* dst, const f32x4 v[2][2], int w, int l15, int lg, int swzv)
{
  #pragma unroll
  for (int mi = 0; mi < 2; ++mi) {
    const int f0 = (w + 4*mi)*16 + lg*4;
    #pragma unroll
    for (int nf = 0; nf < 2; ++nf) {
      const int s = nf*16 + l15;
      uint2 p;
      p.x = pk2(v[mi][nf][0], v[mi][nf][1]);
      p.y = pk2(v[mi][nf][2], v[mi][nf][3]);
      *(uint2*)(dst + ((s*128 + f0) ^ swzv)) = p;
    }
  }
}

// shared_block + dep_block (invocation inv uses dep weights inv*2+{0,1})
// big layout (u16): h at [0:4096], x at [4096:8192]
// NOTE: h is NOT kept in registers across the G1 gemm (16-VGPR saving, r8);
// it is re-read from LDS (bf16, same values G1 consumed) for the residual.
__device__ __forceinline__ void shared_dep(const u16* __restrict__ pk, const float* __restrict__ shiftT,
                                           const u16* binput, u16* big, int inv,
                                           int w, int l15, int lg, int swzv, f32x4 xres[2][2])
{
  f32x4 acc[4][2];
  zero4(acc);
  gemm4<8, 256, 0>(pk + PK_G0_US, binput, w, l15, lg, swzv, acc);
  {
    f32x4 h[2][2];
    glu_epi4(acc, shiftT + 0, w, lg, h);
    __syncthreads();                       // all waves done reading binput (may alias big)
    write_half(big, h, w, l15, lg, swzv);  // h -> big[0:4096]; h regs die here
  }
  __syncthreads();

  zero4(acc);
  gemm4<4, 128, 0>(pk + PK_G1_US, big, w, l15, lg, swzv, acc);
  f32x4 h2[2][2];
  glu_epi4(acc, shiftT + 256, w, lg, h2);
  // reload h (bf16) from LDS and form residual
  #pragma unroll
  for (int mi = 0; mi < 2; ++mi) {
    const int f0 = (w + 4*mi)*16 + lg*4;
    #pragma unroll
    for (int nf = 0; nf < 2; ++nf) {
      const int s = nf*16 + l15;
      uint2 hp = *(const uint2*)(big + ((s*128 + f0) ^ swzv));
      f32x4 hv = unpk4(hp);
      xres[mi][nf] = (hv + h2[mi][nf]) * SQRT_HALF;
    }
  }
  write_half(big + 4096, xres, w, l15, lg, swzv);   // x -> big[4096:8192]
  __syncthreads();

  #pragma unroll
  for (int i = 0; i < 2; ++i) {
    zero4(acc);
    gemm4<4, 128, 0>(pk + PK_DEP_US + (inv*2 + i)*32768, big + 4096, w, l15, lg, swzv, acc);
    f32x4 hd[2][2];
    glu_epi4(acc, shiftT + (2 + inv*2 + i)*256, w, lg, hd);
    __syncthreads();                     // all waves done reading x before in-place update
    #pragma unroll
    for (int mi = 0; mi < 2; ++mi)
      #pragma unroll
      for (int nf = 0; nf < 2; ++nf)
        xres[mi][nf] = (xres[mi][nf] + hd[mi][nf]) * SQRT_HALF;
    write_half(big + 4096, xres, w, l15, lg, swzv);
    __syncthreads();
  }
}

// ---------------- main fused kernel ----------------
// 32 samples/block, 4 waves (256 thr), LDS = 32 KiB, 2 independent blocks/CU.
// __launch_bounds__(256,2) -> 128-VGPR cap; h-reload keeps peak live < 128 (no spill).
__global__ void __launch_bounds__(256, 2)
tabnet_main(const float* __restrict__ inp, const u16* __restrict__ pk,
            const float* __restrict__ shiftT, const float* __restrict__ inSc,
            const float* __restrict__ inSh, float* __restrict__ out)
{
  __shared__ __align__(16) u16 feat[32*256];
  __shared__ __align__(16) u16 big[32*256];
  float2* red2 = (float2*)big;      // [buf*288 + si*9 + w], alias on dead h-region (<=4608B)

  const int tid  = threadIdx.x;
  const int w    = tid >> 6;        // 0..3
  const int lane = tid & 63;
  const int l15  = lane & 15, lg = lane >> 4;
  const int swzv = (l15 & 7) << 3;
  const long long row0 = (long long)blockIdx.x * 32;

  // stage 0: features = BN(inputs) -> feat (bf16, swizzled [sample][256])
  {
    const int f = lane*4;
    const f32x4 sc = *(const f32x4*)(inSc + f);
    const f32x4 sh = *(const f32x4*)(inSh + f);
    #pragma unroll
    for (int j = 0; j < 8; ++j) {
      const int s = j*4 + w;
      f32x4 v = *(const f32x4*)(inp + (row0 + s)*256 + f);
      uint2 p;
      p.x = pk2(v[0]*sc[0] + sh[0], v[1]*sc[1] + sh[1]);
      p.y = pk2(v[2]*sc[2] + sh[2], v[3]*sc[3] + sh[3]);
      *(uint2*)(feat + ((s*256 + f) ^ ((s & 7) << 3))) = p;
    }
  }
  __syncthreads();

  f32x4 xres[2][2];
  shared_dep(pk, shiftT, feat, big, 0, w, l15, lg, swzv, xres);

  __half2 priorH[4][2][2];       // prior packed f16 (pairs over c)
  f32x4 outAg[2];
  {
    const __half2 one2 = __float2half2_rn(1.0f);
    #pragma unroll
    for (int mi = 0; mi < 4; ++mi)
      #pragma unroll
      for (int nf = 0; nf < 2; ++nf) {
        priorH[mi][nf][0] = one2; priorH[mi][nf][1] = one2;
      }
    outAg[0] = splat4(0.0f); outAg[1] = splat4(0.0f);
  }

  #pragma unroll 1
  for (int st = 0; st < 3; ++st) {
    // attention: logits = BN(a @ at_W[st]) * prior, a = x[:,64:128] (big_x KOFF=64)
    f32x4 z[4][2];
    zero4(z);
    gemm4<2, 128, 64>(pk + PK_AT_US + st*16384, big + 4096, w, l15, lg, swzv, z);
    #pragma unroll
    for (int mi = 0; mi < 4; ++mi) {
      const f32x4 bz = *(const f32x4*)(shiftT + (10 + st)*256 + (w + 4*mi)*16 + lg*4);
      #pragma unroll
      for (int nf = 0; nf < 2; ++nf) {
        float2 p0 = __half22float2(priorH[mi][nf][0]);
        float2 p1 = __half22float2(priorH[mi][nf][1]);
        z[mi][nf][0] = (z[mi][nf][0] + bz[0]) * p0.x;
        z[mi][nf][1] = (z[mi][nf][1] + bz[1]) * p0.y;
        z[mi][nf][2] = (z[mi][nf][2] + bz[2]) * p1.x;
        z[mi][nf][3] = (z[mi][nf][3] + bz[3]) * p1.y;
      }
    }

    // ---- rowmax -> tau0 = max - 1 (red2 touches only big[0:4608] = dead h-region)
    float tau[2];
    {
      #pragma unroll
      for (int nf = 0; nf < 2; ++nf) {
        float m = -1e30f;
        #pragma unroll
        for (int mi = 0; mi < 4; ++mi)
          #pragma unroll
          for (int c = 0; c < 4; ++c) m = fmaxf(m, z[mi][nf][c]);
        m = fmaxf(m, __shfl_xor(m, 16, 64));
        m = fmaxf(m, __shfl_xor(m, 32, 64));
        if (lg == 0) { int si = nf*16 + l15; red2[si*9 + w].x = m; }
      }
      __syncthreads();
      #pragma unroll
      for (int nf = 0; nf < 2; ++nf) {
        const int si = nf*16 + l15;
        float m = fmaxf(fmaxf(red2[si*9+0].x, red2[si*9+1].x),
                        fmaxf(red2[si*9+2].x, red2[si*9+3].x));
        tau[nf] = m - 1.0f;
      }
    }

    // ---- Newton iterations, 1 barrier each, uniform early exit
    int buf = 0;
    #pragma unroll 1
    for (int it = 0; it < 12; ++it) {
      buf ^= 1;
      float S[2], C[2];
      #pragma unroll
      for (int nf = 0; nf < 2; ++nf) {
        f32x4 s4 = splat4(0.0f), c4 = splat4(0.0f);
        #pragma unroll
        for (int mi = 0; mi < 4; ++mi)
          #pragma unroll
          for (int c = 0; c < 4; ++c) {
            float d = z[mi][nf][c] - tau[nf];
            s4[c] += fmaxf(d, 0.0f);
            c4[c] += (d > 0.0f) ? 1.0f : 0.0f;
          }
        float S_ = (s4[0] + s4[1]) + (s4[2] + s4[3]);
        float C_ = (c4[0] + c4[1]) + (c4[2] + c4[3]);
        S_ += __shfl_xor(S_, 16, 64); S_ += __shfl_xor(S_, 32, 64);
        C_ += __shfl_xor(C_, 16, 64); C_ += __shfl_xor(C_, 32, 64);
        S[nf] = S_; C[nf] = C_;
      }
      if (lg == 0) {
        #pragma unroll
        for (int nf = 0; nf < 2; ++nf) {
          int si = nf*16 + l15;
          float2 p; p.x = S[nf]; p.y = C[nf];
          red2[buf*288 + si*9 + w] = p;
        }
      }
      __syncthreads();
      bool ok = true;
      float tauN[2];
      #pragma unroll
      for (int nf = 0; nf < 2; ++nf) {
        const int si = nf*16 + l15;
        float Ss = 0.0f, Cs = 0.0f;
        #pragma unroll
        for (int i = 0; i < 4; ++i) { float2 p = red2[buf*288 + si*9 + i]; Ss += p.x; Cs += p.y; }
        ok = ok && (fabsf(Ss - 1.0f) < 1e-5f);
        tauN[nf] = tau[nf] + (Ss - 1.0f) / Cs;
      }
      if (__all(ok)) break;
      #pragma unroll
      for (int nf = 0; nf < 2; ++nf) tau[nf] = tauN[nf];
    }
    __syncthreads();   // all waves done reading red2 before mask overwrites big

    // mask, prior update, masked = mask * features -> big (full [32][256])
    #pragma unroll
    for (int mi = 0; mi < 4; ++mi) {
      const int f0 = (w + 4*mi)*16 + lg*4;
      #pragma unroll
      for (int nf = 0; nf < 2; ++nf) {
        const int si = nf*16 + l15;
        ushort4 fv = *(const ushort4*)(feat + ((si*256 + f0) ^ swzv));
        float m0 = fmaxf(z[mi][nf][0] - tau[nf], 0.0f);
        float m1 = fmaxf(z[mi][nf][1] - tau[nf], 0.0f);
        float m2 = fmaxf(z[mi][nf][2] - tau[nf], 0.0f);
        float m3 = fmaxf(z[mi][nf][3] - tau[nf], 0.0f);
        float2 p0 = __half22float2(priorH[mi][nf][0]);
        float2 p1 = __half22float2(priorH[mi][nf][1]);
        p0.x *= (RELAX - m0); p0.y *= (RELAX - m1);
        p1.x *= (RELAX - m2); p1.y *= (RELAX - m3);
        priorH[mi][nf][0] = __floats2half2_rn(p0.x, p0.y);
        priorH[mi][nf][1] = __floats2half2_rn(p1.x, p1.y);
        uint2 p;
        p.x = pk2(bf2f(fv.x) * m0, bf2f(fv.y) * m1);
        p.y = pk2(bf2f(fv.z) * m2, bf2f(fv.w) * m3);
        *(uint2*)(big + ((si*256 + f0) ^ swzv)) = p;
      }
    }
    __syncthreads();   // masked visible before G0 reads

    shared_dep(pk, shiftT, big, big, st + 1, w, l15, lg, swzv, xres);

    // out_agg += relu(x[:, :64]); features 0..63 = value m-frag mi=0 of each wave
    #pragma unroll
    for (int nf = 0; nf < 2; ++nf)
      #pragma unroll
      for (int c = 0; c < 4; ++c)
        outAg[nf][c] += fmaxf(xres[0][nf][c], 0.0f);
  }

  // final: out = out_agg @ Wout, split-bf16 (hi/lo) for precision
  // stage agg into big[0:2048] hi, big[2048:4096] lo  ([32][64] bf16, swizzled)
  {
    #pragma unroll
    for (int nf = 0; nf < 2; ++nf) {
      const int si = nf*16 + l15;
      const int f0 = w*16 + lg*4;
      ushort4 hi, lo;
      u16 h0 = f2bf(outAg[nf][0]); hi.x = h0; lo.x = f2bf(outAg[nf][0] - bf2f(h0));
      u16 h1 = f2bf(outAg[nf][1]); hi.y = h1; lo.y = f2bf(outAg[nf][1] - bf2f(h1));
      u16 h2v = f2bf(outAg[nf][2]); hi.z = h2v; lo.z = f2bf(outAg[nf][2] - bf2f(h2v));
      u16 h3 = f2bf(outAg[nf][3]); hi.w = h3; lo.w = f2bf(outAg[nf][3] - bf2f(h3));
      *(ushort4*)(big + ((si*64 + f0) ^ swzv)) = hi;
      *(ushort4*)(big + 2048 + ((si*64 + f0) ^ swzv)) = lo;
    }
  }
  __syncthreads();

  // 64x64x(32 samples) GEMM: wave w -> out m-frag w, both sample n-frags
  {
    const int lane64 = lg*16 + l15;
    f32x4 facc[2];
    facc[0] = splat4(0.0f); facc[1] = splat4(0.0f);
    #pragma unroll
    for (int ks = 0; ks < 2; ++ks) {
      short8 aHi = *(const short8*)(pk + PK_WOUT_US   + (size_t)((w*2 + ks)*64 + lane64)*8);
      short8 aLo = *(const short8*)(pk + PK_WOUTLO_US + (size_t)((w*2 + ks)*64 + lane64)*8);
      #pragma unroll
      for (int j = 0; j < 2; ++j) {
        const int si = j*16 + l15;
        short8 bHi = *(const short8*)(big + ((si*64 + ks*32 + lg*8) ^ swzv));
        short8 bLo = *(const short8*)(big + 2048 + ((si*64 + ks*32 + lg*8) ^ swzv));
        facc[j] = __builtin_amdgcn_mfma_f32_16x16x32_bf16(aHi, bHi, facc[j], 0, 0, 0);
        facc[j] = __builtin_amdgcn_mfma_f32_16x16x32_bf16(aHi, bLo, facc[j], 0, 0, 0);
        facc[j] = __builtin_amdgcn_mfma_f32_16x16x32_bf16(aLo, bHi, facc[j], 0, 0, 0);
      }
    }
    #pragma unroll
    for (int j = 0; j < 2; ++j) {
      const int si = j*16 + l15;
      *(f32x4*)(out + (row0 + si)*64 + w*16 + lg*4) = facc[j];
    }
  }
}

// ---------------- launch ----------------
extern "C" void kernel_launch(void* const* d_in, const int* in_sizes, int n_in,
                              void* d_out, int out_size, void* d_ws, size_t ws_size,
                              hipStream_t stream)
{
  const float* inp   = (const float*)d_in[0];
  const float* in_g  = (const float*)d_in[1];
  const float* in_b  = (const float*)d_in[2];
  const float* in_m  = (const float*)d_in[3];
  const float* in_v  = (const float*)d_in[4];
  const float* sh_W0 = (const float*)d_in[5];
  const float* sh_W1 = (const float*)d_in[6];
  const float* sh_g  = (const float*)d_in[7];
  const float* sh_b  = (const float*)d_in[8];
  const float* sh_m  = (const float*)d_in[9];
  const float* sh_v  = (const float*)d_in[10];
  const float* dep_W = (const float*)d_in[11];
  const float* dep_g = (const float*)d_in[12];
  const float* dep_b = (const float*)d_in[13];
  const float* dep_m = (const float*)d_in[14];
  const float* dep_v = (const float*)d_in[15];
  const float* at_W  = (const float*)d_in[16];
  const float* at_g  = (const float*)d_in[17];
  const float* at_b  = (const float*)d_in[18];
  const float* at_m  = (const float*)d_in[19];
  const float* at_v  = (const float*)d_in[20];
  const float* Wout  = (const float*)d_in[21];

  unsigned char* ws = (unsigned char*)d_ws;
  u16*   pk     = (u16*)ws;
  float* shiftT = (float*)(ws + OFF_SHIFT);
  float* scaleT = (float*)(ws + OFF_SCALE);
  float* inSc   = (float*)(ws + OFF_INSC);
  float* inSh   = (float*)(ws + OFF_INSH);

  hipLaunchKernelGGL(prep_bn, dim3(14), dim3(256), 0, stream,
                     in_g, in_b, in_m, in_v, sh_g, sh_b, sh_m, sh_v,
                     dep_g, dep_b, dep_m, dep_v, at_g, at_b, at_m, at_v,
                     shiftT, scaleT, inSc, inSh);
  hipLaunchKernelGGL(prep_pack, dim3(204), dim3(256), 0, stream,
                     sh_W0, sh_W1, dep_W, at_W, Wout, scaleT, pk);
  hipLaunchKernelGGL(tabnet_main, dim3(4096), dim3(256), 0, stream,
                     inp, pk, shiftT, inSc, inSh, (float*)d_out);
}

// Round 9
// 604.533 us; speedup vs baseline: 1.5461x; 1.2677x over previous
//
#include <hip/hip_runtime.h>
#include <hip/hip_bf16.h>
#include <hip/hip_fp16.h>

typedef unsigned short u16;
typedef __attribute__((ext_vector_type(8))) short short8;
typedef __attribute__((ext_vector_type(4))) float f32x4;

#define BN_EPS    1e-3f
#define RELAX     1.3f
#define SQRT_HALF 0.7071067811865476f

// packed-weight offsets (ushort units)
#define PK_G0_US     0
#define PK_G1_US     65536
#define PK_DEP_US    98304
#define PK_AT_US     360448
#define PK_WOUT_US   409600
#define PK_WOUTLO_US 413696
// ws byte offsets
#define OFF_SHIFT 835584
#define OFF_SCALE 848896
#define OFF_INSC  862208
#define OFF_INSH  863232

__device__ __forceinline__ u16 f2bf(float x){
  unsigned u = __float_as_uint(x);
  return (u16)((u + 0x7fffu + ((u >> 16) & 1u)) >> 16);
}
__device__ __forceinline__ float bf2f(u16 h){ return __uint_as_float(((unsigned)h) << 16); }
__device__ __forceinline__ float sigm(float x){ return 1.0f / (1.0f + __expf(-x)); }
__device__ __forceinline__ f32x4 splat4(float x){ f32x4 v; v[0]=x; v[1]=x; v[2]=x; v[3]=x; return v; }

// packed pair f32->bf16 (RTNE) -> one u32 (v_cvt_pk_bf16_f32)
__device__ __forceinline__ unsigned pk2(float a, float b){
  float2 t; t.x = a; t.y = b;
  union { __hip_bfloat162 h; unsigned u; } v;
  v.h = __float22bfloat162_rn(t);
  return v.u;
}
// unpack uint2 (4 bf16, pk2 order) -> f32x4: 2 shifts + 2 ands
__device__ __forceinline__ f32x4 unpk4(uint2 p){
  f32x4 r;
  r[0] = __uint_as_float(p.x << 16);
  r[1] = __uint_as_float(p.x & 0xffff0000u);
  r[2] = __uint_as_float(p.y << 16);
  r[3] = __uint_as_float(p.y & 0xffff0000u);
  return r;
}

// ---------------- prep: BN scale/shift tables ----------------
__global__ void prep_bn(
  const float* in_g, const float* in_b, const float* in_m, const float* in_v,
  const float* sh_g, const float* sh_b, const float* sh_m, const float* sh_v,
  const float* dep_g, const float* dep_b, const float* dep_m, const float* dep_v,
  const float* at_g, const float* at_b, const float* at_m, const float* at_v,
  float* shiftT, float* scaleT, float* inSc, float* inSh)
{
  int r = blockIdx.x, f = threadIdx.x;
  if (r < 13) {
    const float *g, *bb, *mm, *vv;
    if (r < 2)       { g = sh_g + r*256;        bb = sh_b + r*256;        mm = sh_m + r*256;        vv = sh_v + r*256; }
    else if (r < 10) { int j = r-2;  g = dep_g + j*256; bb = dep_b + j*256; mm = dep_m + j*256; vv = dep_v + j*256; }
    else             { int j = r-10; g = at_g  + j*256; bb = at_b  + j*256; mm = at_m  + j*256; vv = at_v  + j*256; }
    float sc = g[f] * rsqrtf(vv[f] + BN_EPS);
    scaleT[r*256 + f] = sc;
    shiftT[r*256 + f] = bb[f] - mm[f]*sc;
  } else {
    float sc = in_g[f] * rsqrtf(in_v[f] + BN_EPS);
    inSc[f] = sc;
    inSh[f] = in_b[f] - in_m[f]*sc;
  }
}

// ---------------- prep: pack weights into MFMA A-fragment order (BN scale folded) ----------------
__global__ void prep_pack(
  const float* sh_W0, const float* sh_W1, const float* dep_W,
  const float* at_W, const float* Wout, const float* scaleT, u16* pk)
{
  int c = blockIdx.x*256 + threadIdx.x;   // 16B chunk id, 0..52223
  const float* W; int K, Nout, srow, base; bool lo = false;
  if (c < 8192)       { W = sh_W0; K = 256; Nout = 256; srow = 0;  base = 0; }
  else if (c < 12288) { W = sh_W1; K = 128; Nout = 256; srow = 1;  base = 8192; }
  else if (c < 45056) { int j = (c-12288) >> 12; W = dep_W + j*32768; K = 128; Nout = 256; srow = 2+j;  base = 12288 + j*4096; }
  else if (c < 51200) { int j = (c-45056) >> 11; W = at_W  + j*16384; K = 64;  Nout = 256; srow = 10+j; base = 45056 + j*2048; }
  else if (c < 51712) { W = Wout; K = 64; Nout = 64; srow = -1; base = 51200; }
  else                { W = Wout; K = 64; Nout = 64; srow = -1; base = 51712; lo = true; }
  int local = c - base;
  int lane  = local & 63;
  int t     = local >> 6;
  int KS    = K >> 5;
  int lsh   = (K == 256) ? 3 : (K == 128) ? 2 : 1;
  int ks    = t & (KS - 1);
  int mf    = t >> lsh;
  int feat  = mf*16 + (lane & 15);
  int k0    = ks*32 + ((lane >> 4) << 3);
  float scl = (srow < 0) ? 1.0f : scaleT[srow*256 + feat];
  u16 v[8];
  #pragma unroll
  for (int j = 0; j < 8; ++j) {
    float x = W[(size_t)(k0 + j)*Nout + feat] * scl;
    u16 h = f2bf(x);
    if (lo) h = f2bf(x - bf2f(h));
    v[j] = h;
  }
  ushort4* d4 = (ushort4*)(pk + (size_t)c*8);
  ushort4 p0; p0.x=v[0]; p0.y=v[1]; p0.z=v[2]; p0.w=v[3];
  ushort4 p1; p1.x=v[4]; p1.y=v[5]; p1.z=v[6]; p1.w=v[7];
  d4[0] = p0; d4[1] = p1;
}

// ---------------- main fused kernel helpers (4 waves, 4 m-frags/wave, 2 n-frags) ----------------
// wave w owns m-frags {w, w+4, w+8, w+12}; value cols = mi 0,1 (frags w,w+4),
// gate cols = mi 2,3 (frags w+8,w+12). n-frags cover 32 samples.
// unroll 1: staging window = a(16)+b(8) VGPRs; unroll 2 spilled (r7/r8, ~130 live > 128 cap).
template<int KS, int LDB, int KOFF>
__device__ __forceinline__ void gemm4(const u16* __restrict__ pk, const u16* bufB,
                                      int w, int l15, int lg, int swzv, f32x4 acc[4][2])
{
  const int lane = lg*16 + l15;
  #pragma unroll 1
  for (int ks = 0; ks < KS; ++ks) {
    short8 b[2];
    #pragma unroll
    for (int nf = 0; nf < 2; ++nf) {
      int idx = (nf*16 + l15)*LDB + KOFF + ks*32 + lg*8;
      b[nf] = *(const short8*)(bufB + (idx ^ swzv));
    }
    short8 a[4];
    #pragma unroll
    for (int mi = 0; mi < 4; ++mi)
      a[mi] = *(const short8*)(pk + (size_t)(((w + 4*mi)*KS + ks)*64 + lane)*8);
    #pragma unroll
    for (int mi = 0; mi < 4; ++mi)
      #pragma unroll
      for (int nf = 0; nf < 2; ++nf)
        acc[mi][nf] = __builtin_amdgcn_mfma_f32_16x16x32_bf16(a[mi], b[nf], acc[mi][nf], 0, 0, 0);
  }
}

__device__ __forceinline__ void zero4(f32x4 acc[4][2]){
  #pragma unroll
  for (int mi = 0; mi < 4; ++mi)
    #pragma unroll
    for (int nf = 0; nf < 2; ++nf)
      acc[mi][nf] = splat4(0.0f);
}

// GLU epilogue: h[mi][nf], mi in {0,1} -> features (w+4*mi)*16 + lg*4
__device__ __forceinline__ void glu_epi4(const f32x4 acc[4][2], const float* __restrict__ shrow,
                                         int w, int lg, f32x4 h[2][2])
{
  #pragma unroll
  for (int mi = 0; mi < 2; ++mi) {
    const int f0 = (w + 4*mi)*16 + lg*4;
    const f32x4 bh = *(const f32x4*)(shrow + f0);
    const f32x4 bg = *(const f32x4*)(shrow + f0 + 128);
    #pragma unroll
    for (int nf = 0; nf < 2; ++nf)
      #pragma unroll
      for (int c = 0; c < 4; ++c) {
        float v = acc[mi][nf][c] + bh[c];
        float g = acc[mi+2][nf][c] + bg[c];
        h[mi][nf][c] = v * sigm(g);
      }
  }
}

// write this wave's 32 features of a 128-wide activation [32][128] bf16 (swizzled)
__device__ __forceinline__ void write_half(u16* dst, const f32x4 v[2][2], int w, int l15, int lg, int swzv)
{
  #pragma unroll
  for (int mi = 0; mi < 2; ++mi) {
    const int f0 = (w + 4*mi)*16 + lg*4;
    #pragma unroll
    for (int nf = 0; nf < 2; ++nf) {
      const int s = nf*16 + l15;
      uint2 p;
      p.x = pk2(v[mi][nf][0], v[mi][nf][1]);
      p.y = pk2(v[mi][nf][2], v[mi][nf][3]);
      *(uint2*)(dst + ((s*128 + f0) ^ swzv)) = p;
    }
  }
}

// shared_block + dep_block (invocation inv uses dep weights inv*2+{0,1})
// big layout (u16): h at [0:4096], x at [4096:8192]
// h is re-read from LDS (bf16) for the residual instead of living in regs across G1.
__device__ __forceinline__ void shared_dep(const u16* __restrict__ pk, const float* __restrict__ shiftT,
                                           const u16* binput, u16* big, int inv,
                                           int w, int l15, int lg, int swzv, f32x4 xres[2][2])
{
  f32x4 acc[4][2];
  zero4(acc);
  gemm4<8, 256, 0>(pk + PK_G0_US, binput, w, l15, lg, swzv, acc);
  {
    f32x4 h[2][2];
    glu_epi4(acc, shiftT + 0, w, lg, h);
    __syncthreads();                       // all waves done reading binput (may alias big)
    write_half(big, h, w, l15, lg, swzv);  // h -> big[0:4096]; h regs die here
  }
  __syncthreads();

  zero4(acc);
  gemm4<4, 128, 0>(pk + PK_G1_US, big, w, l15, lg, swzv, acc);
  f32x4 h2[2][2];
  glu_epi4(acc, shiftT + 256, w, lg, h2);
  // reload h (bf16) from LDS and form residual
  #pragma unroll
  for (int mi = 0; mi < 2; ++mi) {
    const int f0 = (w + 4*mi)*16 + lg*4;
    #pragma unroll
    for (int nf = 0; nf < 2; ++nf) {
      const int s = nf*16 + l15;
      uint2 hp = *(const uint2*)(big + ((s*128 + f0) ^ swzv));
      f32x4 hv = unpk4(hp);
      xres[mi][nf] = (hv + h2[mi][nf]) * SQRT_HALF;
    }
  }
  write_half(big + 4096, xres, w, l15, lg, swzv);   // x -> big[4096:8192]
  __syncthreads();

  #pragma unroll
  for (int i = 0; i < 2; ++i) {
    zero4(acc);
    gemm4<4, 128, 0>(pk + PK_DEP_US + (inv*2 + i)*32768, big + 4096, w, l15, lg, swzv, acc);
    f32x4 hd[2][2];
    glu_epi4(acc, shiftT + (2 + inv*2 + i)*256, w, lg, hd);
    __syncthreads();                     // all waves done reading x before in-place update
    #pragma unroll
    for (int mi = 0; mi < 2; ++mi)
      #pragma unroll
      for (int nf = 0; nf < 2; ++nf)
        xres[mi][nf] = (xres[mi][nf] + hd[mi][nf]) * SQRT_HALF;
    write_half(big + 4096, xres, w, l15, lg, swzv);
    __syncthreads();
  }
}

// ---------------- main fused kernel ----------------
// 32 samples/block, 4 waves (256 thr), LDS = 32 KiB, 2 blocks/CU (8 waves -
// empirical ceiling at 128 VGPR). unroll-1 gemm keeps peak live < 128 -> no spill.
__global__ void __launch_bounds__(256, 2)
tabnet_main(const float* __restrict__ inp, const u16* __restrict__ pk,
            const float* __restrict__ shiftT, const float* __restrict__ inSc,
            const float* __restrict__ inSh, float* __restrict__ out)
{
  __shared__ __align__(16) u16 feat[32*256];
  __shared__ __align__(16) u16 big[32*256];
  float2* red2 = (float2*)big;      // [buf*288 + si*9 + w], alias on dead h-region (<=4608B)

  const int tid  = threadIdx.x;
  const int w    = tid >> 6;        // 0..3
  const int lane = tid & 63;
  const int l15  = lane & 15, lg = lane >> 4;
  const int swzv = (l15 & 7) << 3;
  const long long row0 = (long long)blockIdx.x * 32;

  // stage 0: features = BN(inputs) -> feat (bf16, swizzled [sample][256])
  {
    const int f = lane*4;
    const f32x4 sc = *(const f32x4*)(inSc + f);
    const f32x4 sh = *(const f32x4*)(inSh + f);
    #pragma unroll
    for (int j = 0; j < 8; ++j) {
      const int s = j*4 + w;
      f32x4 v = *(const f32x4*)(inp + (row0 + s)*256 + f);
      uint2 p;
      p.x = pk2(v[0]*sc[0] + sh[0], v[1]*sc[1] + sh[1]);
      p.y = pk2(v[2]*sc[2] + sh[2], v[3]*sc[3] + sh[3]);
      *(uint2*)(feat + ((s*256 + f) ^ ((s & 7) << 3))) = p;
    }
  }
  __syncthreads();

  f32x4 xres[2][2];
  shared_dep(pk, shiftT, feat, big, 0, w, l15, lg, swzv, xres);

  __half2 priorH[4][2][2];       // prior packed f16 (pairs over c)
  f32x4 outAg[2];
  {
    const __half2 one2 = __float2half2_rn(1.0f);
    #pragma unroll
    for (int mi = 0; mi < 4; ++mi)
      #pragma unroll
      for (int nf = 0; nf < 2; ++nf) {
        priorH[mi][nf][0] = one2; priorH[mi][nf][1] = one2;
      }
    outAg[0] = splat4(0.0f); outAg[1] = splat4(0.0f);
  }

  #pragma unroll 1
  for (int st = 0; st < 3; ++st) {
    // attention: logits = BN(a @ at_W[st]) * prior, a = x[:,64:128] (big_x KOFF=64)
    f32x4 z[4][2];
    zero4(z);
    gemm4<2, 128, 64>(pk + PK_AT_US + st*16384, big + 4096, w, l15, lg, swzv, z);
    #pragma unroll
    for (int mi = 0; mi < 4; ++mi) {
      const f32x4 bz = *(const f32x4*)(shiftT + (10 + st)*256 + (w + 4*mi)*16 + lg*4);
      #pragma unroll
      for (int nf = 0; nf < 2; ++nf) {
        float2 p0 = __half22float2(priorH[mi][nf][0]);
        float2 p1 = __half22float2(priorH[mi][nf][1]);
        z[mi][nf][0] = (z[mi][nf][0] + bz[0]) * p0.x;
        z[mi][nf][1] = (z[mi][nf][1] + bz[1]) * p0.y;
        z[mi][nf][2] = (z[mi][nf][2] + bz[2]) * p1.x;
        z[mi][nf][3] = (z[mi][nf][3] + bz[3]) * p1.y;
      }
    }

    // ---- rowmax -> tau0 = max - 1 (red2 touches only big[0:4608] = dead h-region)
    float tau[2];
    {
      #pragma unroll
      for (int nf = 0; nf < 2; ++nf) {
        float m = -1e30f;
        #pragma unroll
        for (int mi = 0; mi < 4; ++mi)
          #pragma unroll
          for (int c = 0; c < 4; ++c) m = fmaxf(m, z[mi][nf][c]);
        m = fmaxf(m, __shfl_xor(m, 16, 64));
        m = fmaxf(m, __shfl_xor(m, 32, 64));
        if (lg == 0) { int si = nf*16 + l15; red2[si*9 + w].x = m; }
      }
      __syncthreads();
      #pragma unroll
      for (int nf = 0; nf < 2; ++nf) {
        const int si = nf*16 + l15;
        float m = fmaxf(fmaxf(red2[si*9+0].x, red2[si*9+1].x),
                        fmaxf(red2[si*9+2].x, red2[si*9+3].x));
        tau[nf] = m - 1.0f;
      }
    }

    // ---- Newton iterations, 1 barrier each, uniform early exit
    int buf = 0;
    #pragma unroll 1
    for (int it = 0; it < 12; ++it) {
      buf ^= 1;
      float S[2], C[2];
      #pragma unroll
      for (int nf = 0; nf < 2; ++nf) {
        f32x4 s4 = splat4(0.0f), c4 = splat4(0.0f);
        #pragma unroll
        for (int mi = 0; mi < 4; ++mi)
          #pragma unroll
          for (int c = 0; c < 4; ++c) {
            float d = z[mi][nf][c] - tau[nf];
            s4[c] += fmaxf(d, 0.0f);
            c4[c] += (d > 0.0f) ? 1.0f : 0.0f;
          }
        float S_ = (s4[0] + s4[1]) + (s4[2] + s4[3]);
        float C_ = (c4[0] + c4[1]) + (c4[2] + c4[3]);
        S_ += __shfl_xor(S_, 16, 64); S_ += __shfl_xor(S_, 32, 64);
        C_ += __shfl_xor(C_, 16, 64); C_ += __shfl_xor(C_, 32, 64);
        S[nf] = S_; C[nf] = C_;
      }
      if (lg == 0) {
        #pragma unroll
        for (int nf = 0; nf < 2; ++nf) {
          int si = nf*16 + l15;
          float2 p; p.x = S[nf]; p.y = C[nf];
          red2[buf*288 + si*9 + w] = p;
        }
      }
      __syncthreads();
      bool ok = true;
      float tauN[2];
      #pragma unroll
      for (int nf = 0; nf < 2; ++nf) {
        const int si = nf*16 + l15;
        float Ss = 0.0f, Cs = 0.0f;
        #pragma unroll
        for (int i = 0; i < 4; ++i) { float2 p = red2[buf*288 + si*9 + i]; Ss += p.x; Cs += p.y; }
        ok = ok && (fabsf(Ss - 1.0f) < 1e-5f);
        tauN[nf] = tau[nf] + (Ss - 1.0f) / Cs;
      }
      if (__all(ok)) break;
      #pragma unroll
      for (int nf = 0; nf < 2; ++nf) tau[nf] = tauN[nf];
    }
    __syncthreads();   // all waves done reading red2 before mask overwrites big

    // mask, prior update, masked = mask * features -> big (full [32][256])
    #pragma unroll
    for (int mi = 0; mi < 4; ++mi) {
      const int f0 = (w + 4*mi)*16 + lg*4;
      #pragma unroll
      for (int nf = 0; nf < 2; ++nf) {
        const int si = nf*16 + l15;
        ushort4 fv = *(const ushort4*)(feat + ((si*256 + f0) ^ swzv));
        float m0 = fmaxf(z[mi][nf][0] - tau[nf], 0.0f);
        float m1 = fmaxf(z[mi][nf][1] - tau[nf], 0.0f);
        float m2 = fmaxf(z[mi][nf][2] - tau[nf], 0.0f);
        float m3 = fmaxf(z[mi][nf][3] - tau[nf], 0.0f);
        float2 p0 = __half22float2(priorH[mi][nf][0]);
        float2 p1 = __half22float2(priorH[mi][nf][1]);
        p0.x *= (RELAX - m0); p0.y *= (RELAX - m1);
        p1.x *= (RELAX - m2); p1.y *= (RELAX - m3);
        priorH[mi][nf][0] = __floats2half2_rn(p0.x, p0.y);
        priorH[mi][nf][1] = __floats2half2_rn(p1.x, p1.y);
        uint2 p;
        p.x = pk2(bf2f(fv.x) * m0, bf2f(fv.y) * m1);
        p.y = pk2(bf2f(fv.z) * m2, bf2f(fv.w) * m3);
        *(uint2*)(big + ((si*256 + f0) ^ swzv)) = p;
      }
    }
    __syncthreads();   // masked visible before G0 reads

    shared_dep(pk, shiftT, big, big, st + 1, w, l15, lg, swzv, xres);

    // out_agg += relu(x[:, :64]); features 0..63 = value m-frag mi=0 of each wave
    #pragma unroll
    for (int nf = 0; nf < 2; ++nf)
      #pragma unroll
      for (int c = 0; c < 4; ++c)
        outAg[nf][c] += fmaxf(xres[0][nf][c], 0.0f);
  }

  // final: out = out_agg @ Wout, split-bf16 (hi/lo) for precision
  // stage agg into big[0:2048] hi, big[2048:4096] lo  ([32][64] bf16, swizzled)
  {
    #pragma unroll
    for (int nf = 0; nf < 2; ++nf) {
      const int si = nf*16 + l15;
      const int f0 = w*16 + lg*4;
      ushort4 hi, lo;
      u16 h0 = f2bf(outAg[nf][0]); hi.x = h0; lo.x = f2bf(outAg[nf][0] - bf2f(h0));
      u16 h1 = f2bf(outAg[nf][1]); hi.y = h1; lo.y = f2bf(outAg[nf][1] - bf2f(h1));
      u16 h2v = f2bf(outAg[nf][2]); hi.z = h2v; lo.z = f2bf(outAg[nf][2] - bf2f(h2v));
      u16 h3 = f2bf(outAg[nf][3]); hi.w = h3; lo.w = f2bf(outAg[nf][3] - bf2f(h3));
      *(ushort4*)(big + ((si*64 + f0) ^ swzv)) = hi;
      *(ushort4*)(big + 2048 + ((si*64 + f0) ^ swzv)) = lo;
    }
  }
  __syncthreads();

  // 64x64x(32 samples) GEMM: wave w -> out m-frag w, both sample n-frags
  {
    const int lane64 = lg*16 + l15;
    f32x4 facc[2];
    facc[0] = splat4(0.0f); facc[1] = splat4(0.0f);
    #pragma unroll
    for (int ks = 0; ks < 2; ++ks) {
      short8 aHi = *(const short8*)(pk + PK_WOUT_US   + (size_t)((w*2 + ks)*64 + lane64)*8);
      short8 aLo = *(const short8*)(pk + PK_WOUTLO_US + (size_t)((w*2 + ks)*64 + lane64)*8);
      #pragma unroll
      for (int j = 0; j < 2; ++j) {
        const int si = j*16 + l15;
        short8 bHi = *(const short8*)(big + ((si*64 + ks*32 + lg*8) ^ swzv));
        short8 bLo = *(const short8*)(big + 2048 + ((si*64 + ks*32 + lg*8) ^ swzv));
        facc[j] = __builtin_amdgcn_mfma_f32_16x16x32_bf16(aHi, bHi, facc[j], 0, 0, 0);
        facc[j] = __builtin_amdgcn_mfma_f32_16x16x32_bf16(aHi, bLo, facc[j], 0, 0, 0);
        facc[j] = __builtin_amdgcn_mfma_f32_16x16x32_bf16(aLo, bHi, facc[j], 0, 0, 0);
      }
    }
    #pragma unroll
    for (int j = 0; j < 2; ++j) {
      const int si = j*16 + l15;
      *(f32x4*)(out + (row0 + si)*64 + w*16 + lg*4) = facc[j];
    }
  }
}

// ---------------- launch ----------------
extern "C" void kernel_launch(void* const* d_in, const int* in_sizes, int n_in,
                              void* d_out, int out_size, void* d_ws, size_t ws_size,
                              hipStream_t stream)
{
  const float* inp   = (const float*)d_in[0];
  const float* in_g  = (const float*)d_in[1];
  const float* in_b  = (const float*)d_in[2];
  const float* in_m  = (const float*)d_in[3];
  const float* in_v  = (const float*)d_in[4];
  const float* sh_W0 = (const float*)d_in[5];
  const float* sh_W1 = (const float*)d_in[6];
  const float* sh_g  = (const float*)d_in[7];
  const float* sh_b  = (const float*)d_in[8];
  const float* sh_m  = (const float*)d_in[9];
  const float* sh_v  = (const float*)d_in[10];
  const float* dep_W = (const float*)d_in[11];
  const float* dep_g = (const float*)d_in[12];
  const float* dep_b = (const float*)d_in[13];
  const float* dep_m = (const float*)d_in[14];
  const float* dep_v = (const float*)d_in[15];
  const float* at_W  = (const float*)d_in[16];
  const float* at_g  = (const float*)d_in[17];
  const float* at_b  = (const float*)d_in[18];
  const float* at_m  = (const float*)d_in[19];
  const float* at_v  = (const float*)d_in[20];
  const float* Wout  = (const float*)d_in[21];

  unsigned char* ws = (unsigned char*)d_ws;
  u16*   pk     = (u16*)ws;
  float* shiftT = (float*)(ws + OFF_SHIFT);
  float* scaleT = (float*)(ws + OFF_SCALE);
  float* inSc   = (float*)(ws + OFF_INSC);
  float* inSh   = (float*)(ws + OFF_INSH);

  hipLaunchKernelGGL(prep_bn, dim3(14), dim3(256), 0, stream,
                     in_g, in_b, in_m, in_v, sh_g, sh_b, sh_m, sh_v,
                     dep_g, dep_b, dep_m, dep_v, at_g, at_b, at_m, at_v,
                     shiftT, scaleT, inSc, inSh);
  hipLaunchKernelGGL(prep_pack, dim3(204), dim3(256), 0, stream,
                     sh_W0, sh_W1, dep_W, at_W, Wout, scaleT, pk);
  hipLaunchKernelGGL(tabnet_main, dim3(4096), dim3(256), 0, stream,
                     inp, pk, shiftT, inSc, inSh, (float*)d_out);
}